// Round 9
// baseline (946.848 us; speedup 1.0000x reference)
//
#include <hip/hip_runtime.h>
#include <cstdint>
#include <cstddef>

// ---------------------------------------------------------------------------
// MaxKGIN. R9: gather3 pair-column ownership (one u64 mask path per lane,
// ~40% less VALU than r8's split-column rank-select) + dynamic row stealing;
// GEMMs widened to 512-thread blocks (2 blocks/CU was LDS-capped at 8
// waves/CU -> now 16). CSR build: two-level binning. maxk: radix-select.
// ---------------------------------------------------------------------------

typedef __attribute__((ext_vector_type(8))) short bf16x8;
typedef __attribute__((ext_vector_type(4))) float f32x4;

#define BSHIFT 8
#define NBUK 512  // covers dst>>8 for n <= 131072

__device__ __forceinline__ unsigned rne_bf16(float v) {
  unsigned u = __float_as_uint(v);
  return (u + 0x7fffu + ((u >> 16) & 1u)) >> 16;
}

// ---------------- fused W^T build: all 4 weights -> hi/lo bf16 --------------
__global__ __launch_bounds__(256) void wt_build_all_kernel(
    const float* __restrict__ W_in, const float* __restrict__ W_lin,
    const float* __restrict__ W_out, short* __restrict__ out) {
  const int i = blockIdx.x * 256 + threadIdx.x;
  if (i >= 57344) return;
  const float* W;
  int nout, local;
  short* H;
  if (i < 16384) {
    W = W_in; nout = 128; local = i; H = out;
  } else if (i < 32768) {
    W = W_lin; nout = 128; local = i - 16384; H = out + 32768;
  } else if (i < 49152) {
    W = W_lin + 16384; nout = 128; local = i - 32768; H = out + 65536;
  } else {
    W = W_out; nout = 64; local = i - 49152; H = out + 98304;
  }
  const int nn = local >> 7, k = local & 127;
  const float v = W[k * nout + nn];
  const unsigned hb = rne_bf16(v);
  const float hf = __uint_as_float(hb << 16);
  const unsigned lb = rne_bf16(v - hf);
  H[local] = (short)hb;
  H[local + nout * 128] = (short)lb;
}

// ---------------- GEMM A (fp32 X): Yh/Yl = split(relu(X@W+b)) ---------------
// 512 threads / 8 waves per block; 128-row tiles; W^T hi/lo staged once.
__global__ __launch_bounds__(512, 2) void gemm_in_kernel(
    const float* __restrict__ X, const short* __restrict__ WtH,
    const short* __restrict__ WtL, const float* __restrict__ bias,
    short* __restrict__ Yh, short* __restrict__ Yl, int nrows, int ntiles) {
  constexpr int NOUT = 128;
  constexpr int NT = NOUT / 16;
  constexpr int LDB = 128 * 2 + 16;
  constexpr int PLANE = NOUT * LDB;
  __shared__ char lds[2 * PLANE];

  const int tid = threadIdx.x;
  for (int u = tid; u < 2 * NOUT * 16; u += 512) {
    const int plane = u / (NOUT * 16);
    const int v = u % (NOUT * 16);
    const int nrow = v >> 4, seg = v & 15;
    const short* src = plane ? WtL : WtH;
    const float4 d = *(const float4*)&src[nrow * 128 + seg * 8];
    *(float4*)&lds[plane * PLANE + nrow * LDB + seg * 16] = d;
  }
  __syncthreads();

  const int lane = tid & 63;
  const int wv = tid >> 6;  // 0..7
  const int li = lane & 15;
  const int kg = lane >> 4;

  float bv[NT];
#pragma unroll
  for (int t = 0; t < NT; ++t) bv[t] = bias[t * 16 + li];

  for (int tile = blockIdx.x; tile < ntiles; tile += gridDim.x) {
    const int row = tile * 128 + wv * 16 + li;
    const int rowc = (row < nrows) ? row : (nrows - 1);
    const float* xrow = X + (size_t)rowc * 128;

    f32x4 acc[NT];
#pragma unroll
    for (int t = 0; t < NT; ++t) acc[t] = (f32x4){0.f, 0.f, 0.f, 0.f};

#pragma unroll
    for (int c = 0; c < 4; ++c) {
      const float4 p0 = *(const float4*)&xrow[c * 32 + kg * 8];
      const float4 p1 = *(const float4*)&xrow[c * 32 + kg * 8 + 4];
      float f[8] = {p0.x, p0.y, p0.z, p0.w, p1.x, p1.y, p1.z, p1.w};
      bf16x8 ah, al;
#pragma unroll
      for (int e = 0; e < 8; ++e) {
        const unsigned hb = rne_bf16(f[e]);
        const float hf = __uint_as_float(hb << 16);
        ah[e] = (short)hb;
        al[e] = (short)rne_bf16(f[e] - hf);
      }
      const int kb = c * 64 + kg * 16;
#pragma unroll
      for (int t = 0; t < NT; ++t) {
        const int boff = (t * 16 + li) * LDB + kb;
        const bf16x8 bh = *(const bf16x8*)&lds[boff];
        const bf16x8 bl = *(const bf16x8*)&lds[PLANE + boff];
        acc[t] = __builtin_amdgcn_mfma_f32_16x16x32_bf16(al, bh, acc[t], 0, 0, 0);
        acc[t] = __builtin_amdgcn_mfma_f32_16x16x32_bf16(ah, bl, acc[t], 0, 0, 0);
        acc[t] = __builtin_amdgcn_mfma_f32_16x16x32_bf16(ah, bh, acc[t], 0, 0, 0);
      }
    }

    const int orow = tile * 128 + wv * 16 + kg * 4;
#pragma unroll
    for (int t = 0; t < NT; ++t) {
      const int col = t * 16 + li;
#pragma unroll
      for (int r = 0; r < 4; ++r) {
        const int rr = orow + r;
        if (rr < nrows) {
          const float o = fmaxf(acc[t][r] + bv[t], 0.f);
          const unsigned hb = rne_bf16(o);
          const float hf = __uint_as_float(hb << 16);
          Yh[(size_t)rr * 128 + col] = (short)hb;
          Yl[(size_t)rr * 128 + col] = (short)rne_bf16(o - hf);
        }
      }
    }
  }
}

// ---------------- GEMM B (bf16-plane X): Y = X@W + b (fp32 out) -------------
template <int NOUT>
__global__ __launch_bounds__(512, 2) void gemm_pl_kernel(
    const short* __restrict__ Xh, const short* __restrict__ Xl,
    const short* __restrict__ WtH, const short* __restrict__ WtL,
    const float* __restrict__ bias, float* __restrict__ Y, int nrows,
    int ntiles) {
  constexpr int NT = NOUT / 16;
  constexpr int LDB = 128 * 2 + 16;
  constexpr int PLANE = NOUT * LDB;
  __shared__ char lds[2 * PLANE];

  const int tid = threadIdx.x;
  for (int u = tid; u < 2 * NOUT * 16; u += 512) {
    const int plane = u / (NOUT * 16);
    const int v = u % (NOUT * 16);
    const int nrow = v >> 4, seg = v & 15;
    const short* src = plane ? WtL : WtH;
    const float4 d = *(const float4*)&src[nrow * 128 + seg * 8];
    *(float4*)&lds[plane * PLANE + nrow * LDB + seg * 16] = d;
  }
  __syncthreads();

  const int lane = tid & 63;
  const int wv = tid >> 6;  // 0..7
  const int li = lane & 15;
  const int kg = lane >> 4;

  float bv[NT];
#pragma unroll
  for (int t = 0; t < NT; ++t) bv[t] = bias[t * 16 + li];

  for (int tile = blockIdx.x; tile < ntiles; tile += gridDim.x) {
    const int row = tile * 128 + wv * 16 + li;
    const int rowc = (row < nrows) ? row : (nrows - 1);
    const short* xh = Xh + (size_t)rowc * 128;
    const short* xl = Xl + (size_t)rowc * 128;

    f32x4 acc[NT];
#pragma unroll
    for (int t = 0; t < NT; ++t) acc[t] = (f32x4){0.f, 0.f, 0.f, 0.f};

#pragma unroll
    for (int c = 0; c < 4; ++c) {
      const bf16x8 ah = *(const bf16x8*)&xh[c * 32 + kg * 8];
      const bf16x8 al = *(const bf16x8*)&xl[c * 32 + kg * 8];
      const int kb = c * 64 + kg * 16;
#pragma unroll
      for (int t = 0; t < NT; ++t) {
        const int boff = (t * 16 + li) * LDB + kb;
        const bf16x8 bh = *(const bf16x8*)&lds[boff];
        const bf16x8 bl = *(const bf16x8*)&lds[PLANE + boff];
        acc[t] = __builtin_amdgcn_mfma_f32_16x16x32_bf16(al, bh, acc[t], 0, 0, 0);
        acc[t] = __builtin_amdgcn_mfma_f32_16x16x32_bf16(ah, bl, acc[t], 0, 0, 0);
        acc[t] = __builtin_amdgcn_mfma_f32_16x16x32_bf16(ah, bh, acc[t], 0, 0, 0);
      }
    }

    const int orow = tile * 128 + wv * 16 + kg * 4;
#pragma unroll
    for (int t = 0; t < NT; ++t) {
      const int col = t * 16 + li;
#pragma unroll
      for (int r = 0; r < 4; ++r) {
        const int rr = orow + r;
        if (rr < nrows) Y[(size_t)rr * NOUT + col] = acc[t][r] + bv[t];
      }
    }
  }
}

// ---------------- MaxK: radix-select top-16 -> (mask, col-ordered vals) -----
__global__ __launch_bounds__(256) void maxk_kernel(
    const float* __restrict__ T, ulonglong2* __restrict__ Ms,
    float* __restrict__ Vs, int nrows) {
  const int lane = threadIdx.x & 63;
  const int wid = threadIdx.x >> 6;
  const unsigned long long below = ((unsigned long long)1 << lane) - 1;

  for (int row = blockIdx.x * 4 + wid; row < nrows; row += gridDim.x * 4) {
    const float o0 = T[(size_t)row * 128 + lane];
    const float o1 = T[(size_t)row * 128 + 64 + lane];
    const unsigned u0 = __float_as_uint(o0);
    const unsigned u1 = __float_as_uint(o1);
    const unsigned k0 = u0 ^ (((unsigned)((int)u0 >> 31)) | 0x80000000u);
    const unsigned k1 = u1 ^ (((unsigned)((int)u1 >> 31)) | 0x80000000u);

    unsigned P = 0;
    int kth = 16;
#pragma unroll
    for (int b = 31; b >= 0; --b) {
      const unsigned long long ball0 = __ballot(((k0 ^ P) >> b) == 1u);
      const unsigned long long ball1 = __ballot(((k1 ^ P) >> b) == 1u);
      const int c = __popcll(ball0) + __popcll(ball1);
      if (c >= kth)
        P |= (1u << b);
      else
        kth -= c;
    }
    const bool gt0 = k0 > P, gt1 = k1 > P;
    const unsigned long long g0 = __ballot(gt0);
    const unsigned long long g1 = __ballot(gt1);
    const int need = 16 - __popcll(g0) - __popcll(g1);
    const unsigned long long e0 = __ballot(k0 == P);
    const unsigned long long e1 = __ballot(k1 == P);
    const int need1 = need - __popcll(e0);
    const bool s0 = ((e0 >> lane) & 1) && ((int)__popcll(e0 & below) < need);
    const bool s1 = ((e1 >> lane) & 1) && ((int)__popcll(e1 & below) < need1);
    const unsigned long long m0 = __ballot(gt0 || s0);
    const unsigned long long m1 = __ballot(gt1 || s1);

    if (lane == 0) Ms[row] = make_ulonglong2(m0, m1);
    if ((m0 >> lane) & 1)
      Vs[(size_t)row * 16 + __popcll(m0 & below)] = o0;
    if ((m1 >> lane) & 1)
      Vs[(size_t)row * 16 + __popcll(m0) + __popcll(m1 & below)] = o1;
  }
}

// ---------------- CSR build v2: two-level binning ---------------------------
__global__ __launch_bounds__(256) void bhist_kernel(const int* __restrict__ dst,
                                                    int* __restrict__ BC,
                                                    int E) {
  __shared__ int bh[NBUK];
  for (int i = threadIdx.x; i < NBUK; i += 256) bh[i] = 0;
  __syncthreads();
  const int stride = gridDim.x * 256;
  for (int e = blockIdx.x * 256 + threadIdx.x; e < E; e += stride)
    atomicAdd(&bh[dst[e] >> BSHIFT], 1);
  __syncthreads();
  for (int i = threadIdx.x; i < NBUK; i += 256)
    if (bh[i]) atomicAdd(&BC[i], bh[i]);
}

__global__ __launch_bounds__(NBUK) void bscan_kernel(
    const int* __restrict__ BC, int* __restrict__ bases,
    int* __restrict__ bcur, int* __restrict__ rs, int n, int E) {
  __shared__ int sc[NBUK];
  const int t = threadIdx.x;
  const int c = BC[t];
  sc[t] = c;
  __syncthreads();
  for (int st = 1; st < NBUK; st <<= 1) {
    const int v = sc[t];
    const int u = (t >= st) ? sc[t - st] : 0;
    __syncthreads();
    sc[t] = v + u;
    __syncthreads();
  }
  const int excl = sc[t] - c;
  bases[t] = excl;
  bcur[t] = excl;
  if (t == 0) rs[n] = E;
}

__global__ __launch_bounds__(256) void bin_kernel(
    const int* __restrict__ src, const int* __restrict__ dst,
    int* __restrict__ bcur, uint2* __restrict__ binned, int E, int chunk) {
  __shared__ int cnt[NBUK], off[NBUK], gbase[NBUK];
  __shared__ unsigned short bktof[4096];
  __shared__ uint2 buf[4096];
  const int t = threadIdx.x;
  const int beg = blockIdx.x * chunk;
  const int m = min(chunk, E - beg);
  if (m <= 0) return;

  for (int i = t; i < NBUK; i += 256) cnt[i] = 0;
  __syncthreads();

  int d[16], s[16], lp[16], bk[16];
#pragma unroll
  for (int i = 0; i < 16; ++i) {
    const int j = i * 256 + t;
    if (j < m) {
      d[i] = dst[beg + j];
      s[i] = src[beg + j];
      bk[i] = d[i] >> BSHIFT;
      lp[i] = atomicAdd(&cnt[bk[i]], 1);
    } else {
      bk[i] = -1;
    }
  }
  __syncthreads();

  for (int i = t; i < NBUK; i += 256) off[i] = cnt[i];
  __syncthreads();
  for (int st = 1; st < NBUK; st <<= 1) {
    int v0, v1, u0, u1;
    {
      const int i0 = t, i1 = t + 256;
      v0 = off[i0]; u0 = (i0 >= st) ? off[i0 - st] : 0;
      v1 = off[i1]; u1 = (i1 >= st) ? off[i1 - st] : 0;
    }
    __syncthreads();
    off[t] = v0 + u0;
    off[t + 256] = v1 + u1;
    __syncthreads();
  }

  for (int i = t; i < NBUK; i += 256) {
    const int c = cnt[i];
    if (c > 0) {
      gbase[i] = atomicAdd(&bcur[i], c);
      const int e0 = off[i] - c;
      for (int k = 0; k < c; ++k) bktof[e0 + k] = (unsigned short)i;
    }
  }
  __syncthreads();

#pragma unroll
  for (int i = 0; i < 16; ++i) {
    if (bk[i] >= 0) {
      buf[(off[bk[i]] - cnt[bk[i]]) + lp[i]] =
          make_uint2((unsigned)d[i], (unsigned)s[i]);
    }
  }
  __syncthreads();

  for (int j = t; j < m; j += 256) {
    const int b = bktof[j];
    const int e0 = off[b] - cnt[b];
    binned[gbase[b] + (j - e0)] = buf[j];
  }
}

__global__ __launch_bounds__(256) void bbuild_kernel(
    const int* __restrict__ bases, const int* __restrict__ BC,
    const uint2* __restrict__ binned, int* __restrict__ rs,
    int* __restrict__ csr_src, int n) {
  __shared__ int nd[256], sc[256], cur[256];
  const int b = blockIdx.x;
  const int t = threadIdx.x;
  const int base = bases[b];
  const int count = BC[b];
  const int node0 = b << BSHIFT;

  nd[t] = 0;
  __syncthreads();
  for (int i = t; i < count; i += 256)
    atomicAdd(&nd[binned[base + i].x & 255], 1);
  __syncthreads();

  sc[t] = nd[t];
  __syncthreads();
  for (int st = 1; st < 256; st <<= 1) {
    const int v = sc[t];
    const int u = (t >= st) ? sc[t - st] : 0;
    __syncthreads();
    sc[t] = v + u;
    __syncthreads();
  }
  const int excl = sc[t] - nd[t];
  cur[t] = excl;
  if (node0 + t < n) rs[node0 + t] = base + excl;
  __syncthreads();

  for (int i = t; i < count; i += 256) {
    const uint2 p = binned[base + i];
    const int pos = atomicAdd(&cur[p.x & 255], 1);
    csr_src[base + pos] = (int)p.y;
  }
}

// ---------------- Gather v3: pair-column rank-select, dynamic stealing ------
// lane owns cols {2i, 2i+1} in ONE u64 mask half; below-mask is per-lane
// constant; both outputs pack to one dword store per plane.
__global__ __launch_bounds__(256) void gather3_kernel(
    const int* __restrict__ rs, const int* __restrict__ csr_src,
    const ulonglong2* __restrict__ Ms, const float* __restrict__ Vs,
    const float* __restrict__ eps_p, unsigned* __restrict__ Ah2,
    unsigned* __restrict__ Al2, int* __restrict__ work, int nrows) {
  __shared__ __align__(16) float sv[4][16][16];
  __shared__ ulonglong2 sm[4][16];
  const int lane = threadIdx.x & 63;
  const int wid = threadIdx.x >> 6;
  const float e1 = 1.0f + *eps_p;
  const int half = lane >> 5;
  const int b0 = (lane & 31) * 2;
  const unsigned long long below0 = ((unsigned long long)1 << b0) - 1;
  const int ee = lane >> 2;
  const int q = lane & 3;

  for (;;) {
    int chunk;
    if (lane == 0) chunk = atomicAdd(work, 1);
    chunk = __shfl(chunk, 0);
    const int row0 = chunk * 8;
    if (row0 >= nrows) break;
    const int rend = min(row0 + 8, nrows);

    for (int r = row0; r < rend; ++r) {
      float acc0 = 0.f, acc1 = 0.f;
      const int beg = rs[r], end = rs[r + 1];

      for (int base = beg; base < end; base += 16) {
        const int cnt = min(16, end - base);
        if (ee < cnt) {
          const int s = csr_src[base + ee];
          if (q == 0) sm[wid][ee] = Ms[s];
          const float4 v = *(const float4*)&Vs[(size_t)s * 16 + q * 4];
          *(float4*)&sv[wid][ee][q * 4] = v;
        }
        // same-wave DS ops are in-order; no barrier needed
        for (int e = 0; e < cnt; ++e) {
          const ulonglong2 mm = sm[wid][e];
          const unsigned long long m = half ? mm.y : mm.x;
          const int rbase = half ? __popcll(mm.x) : 0;
          const int rk0 = rbase + (int)__popcll(m & below0);
          const unsigned t2 = (unsigned)(m >> b0) & 3u;
          const float v0 = sv[wid][e][rk0 & 15];
          const float v1 = sv[wid][e][(rk0 + (int)(t2 & 1)) & 15];
          if (t2 & 1) acc0 += v0;
          if (t2 & 2) acc1 += v1;
        }
      }

      // self term: (1+eps) * h_sparse[r]
      {
        const ulonglong2 mr = Ms[r];
        const unsigned long long m = half ? mr.y : mr.x;
        const int rbase = half ? __popcll(mr.x) : 0;
        const int rk0 = rbase + (int)__popcll(m & below0);
        const unsigned t2 = (unsigned)(m >> b0) & 3u;
        if (t2 & 1) acc0 += e1 * Vs[(size_t)r * 16 + rk0];
        if (t2 & 2) acc1 += e1 * Vs[(size_t)r * 16 + rk0 + (int)(t2 & 1)];
      }

      // pack adjacent cols into one dword per plane (coalesced)
      const unsigned h0 = rne_bf16(acc0), h1 = rne_bf16(acc1);
      const unsigned l0 = rne_bf16(acc0 - __uint_as_float(h0 << 16));
      const unsigned l1 = rne_bf16(acc1 - __uint_as_float(h1 << 16));
      const int di = r * 64 + half * 32 + (lane & 31);
      Ah2[di] = h0 | (h1 << 16);
      Al2[di] = l0 | (l1 << 16);
    }
  }
}

// ---------------------------------------------------------------------------
extern "C" void kernel_launch(void* const* d_in, const int* in_sizes, int n_in,
                              void* d_out, int out_size, void* d_ws,
                              size_t ws_size, hipStream_t stream) {
  const float* x = (const float*)d_in[0];
  const int* src = (const int*)d_in[1];
  const int* dst = (const int*)d_in[2];
  const float* W_in = (const float*)d_in[3];
  const float* b_in = (const float*)d_in[4];
  const float* W_lin = (const float*)d_in[5];
  const float* b_lin = (const float*)d_in[6];
  const float* eps = (const float*)d_in[7];
  const float* W_out = (const float*)d_in[8];
  const float* b_out = (const float*)d_in[9];
  float* out = (float*)d_out;

  const int n = in_sizes[0] / 128;
  const int E = in_sizes[1];

  char* w = (char*)d_ws;
  float* B = (float*)w;               w += (size_t)n * 128 * 4;
  ulonglong2* Ms = (ulonglong2*)w;    w += (size_t)n * 16;
  float* Vs = (float*)w;              w += (size_t)n * 16 * 4;
  int* rs = (int*)w;                  w += (size_t)(n + 1) * 4;
  int* csr_src = (int*)w;             w += (size_t)E * 4;
  uint2* binned = (uint2*)w;          w += (size_t)E * 8;
  int* BC = (int*)w;                  w += NBUK * 4;
  int* bases = (int*)w;               w += NBUK * 4;
  int* bcur = (int*)w;                w += NBUK * 4;
  short* wtAll = (short*)w;           w += (size_t)114688 * 2;
  short* Ah = (short*)w;              w += (size_t)n * 128 * 2;
  short* Al = (short*)w;              w += (size_t)n * 128 * 2;
  int* wk = (int*)w;                  w += 16;

  short* wtIn = wtAll;
  short* wtL0 = wtAll + 32768;
  short* wtL1 = wtAll + 65536;
  short* wtOut = wtAll + 98304;

  const int gtiles = (n + 127) / 128;        // 128-row tiles (512-thr blocks)
  const int gblocks = (gtiles + 1) / 2;      // 2 tiles per block, all resident
  const int nbuk_eff = (n + 255) >> BSHIFT;
  const int chunk = 4000;
  const int cblocks = (E + chunk - 1) / chunk;
  const dim3 blk(256);

  // ---- CSR build ----
  hipMemsetAsync(BC, 0, NBUK * 4, stream);
  hipMemsetAsync(wk, 0, 16, stream);
  bhist_kernel<<<256, blk, 0, stream>>>(dst, BC, E);
  bscan_kernel<<<1, NBUK, 0, stream>>>(BC, bases, bcur, rs, n, E);
  bin_kernel<<<cblocks, blk, 0, stream>>>(src, dst, bcur, binned, E, chunk);
  bbuild_kernel<<<nbuk_eff, blk, 0, stream>>>(bases, BC, binned, rs, csr_src,
                                              n);

  // ---- weights -> hi/lo bf16 ----
  wt_build_all_kernel<<<(57344 + 255) / 256, blk, 0, stream>>>(W_in, W_lin,
                                                               W_out, wtAll);

  // ---- h = relu(x @ W_in + b_in) -> planes ----
  gemm_in_kernel<<<gblocks, dim3(512), 0, stream>>>(x, wtIn, wtIn + 16384,
                                                    b_in, Ah, Al, n, gtiles);

  for (int l = 0; l < 2; ++l) {
    short* wt = l ? wtL1 : wtL0;
    gemm_pl_kernel<128><<<gblocks, dim3(512), 0, stream>>>(
        Ah, Al, wt, wt + 16384, b_lin + (size_t)l * 128, B, n, gtiles);
    maxk_kernel<<<2048, blk, 0, stream>>>(B, Ms, Vs, n);
    gather3_kernel<<<2048, blk, 0, stream>>>(rs, csr_src, Ms, Vs, eps + l,
                                             (unsigned*)Ah, (unsigned*)Al,
                                             wk + l, n);
  }

  gemm_pl_kernel<64><<<gblocks, dim3(512), 0, stream>>>(
      Ah, Al, wtOut, wtOut + 8192, b_out, out, n, gtiles);
}

// Round 11
// 619.477 us; speedup vs baseline: 1.5285x; 1.5285x over previous
//
#include <hip/hip_runtime.h>
#include <cstdint>
#include <cstddef>

// ---------------------------------------------------------------------------
// MaxKGIN. R11: r10 FAILED (bf16-quantized messages -> absmax 5.75 > 5.36).
// Restore r8 base (fp32 messages, passed @ 4.75). Within-run A/B:
//   layer 0: gather2 (rank-select, VALU-bound, known 109us)
//   layer 1: gather5 (dense fp32 float2 rows: 1 coalesced 8B load + 2 adds
//            per lane-edge, ~5 wave-instr/edge, L3-served traffic)
// maxk emits both formats. GEMMs: split-bf16 MFMA. CSR: two-level binning.
// ---------------------------------------------------------------------------

typedef __attribute__((ext_vector_type(8))) short bf16x8;
typedef __attribute__((ext_vector_type(4))) float f32x4;

#define BSHIFT 8
#define NBUK 512  // covers dst>>8 for n <= 131072

__device__ __forceinline__ unsigned rne_bf16(float v) {
  unsigned u = __float_as_uint(v);
  return (u + 0x7fffu + ((u >> 16) & 1u)) >> 16;
}

// ---------------- fused W^T build: all 4 weights -> hi/lo bf16 --------------
__global__ __launch_bounds__(256) void wt_build_all_kernel(
    const float* __restrict__ W_in, const float* __restrict__ W_lin,
    const float* __restrict__ W_out, short* __restrict__ out) {
  const int i = blockIdx.x * 256 + threadIdx.x;
  if (i >= 57344) return;
  const float* W;
  int nout, local;
  short* H;
  if (i < 16384) {
    W = W_in; nout = 128; local = i; H = out;
  } else if (i < 32768) {
    W = W_lin; nout = 128; local = i - 16384; H = out + 32768;
  } else if (i < 49152) {
    W = W_lin + 16384; nout = 128; local = i - 32768; H = out + 65536;
  } else {
    W = W_out; nout = 64; local = i - 49152; H = out + 98304;
  }
  const int nn = local >> 7, k = local & 127;
  const float v = W[k * nout + nn];
  const unsigned hb = rne_bf16(v);
  const float hf = __uint_as_float(hb << 16);
  const unsigned lb = rne_bf16(v - hf);
  H[local] = (short)hb;
  H[local + nout * 128] = (short)lb;
}

// ---------------- GEMM A (fp32 X): Yh/Yl = split(relu(X@W+b)) ---------------
__global__ __launch_bounds__(256, 2) void gemm_in_kernel(
    const float* __restrict__ X, const short* __restrict__ WtH,
    const short* __restrict__ WtL, const float* __restrict__ bias,
    short* __restrict__ Yh, short* __restrict__ Yl, int nrows, int ntiles) {
  constexpr int NOUT = 128;
  constexpr int NT = NOUT / 16;
  constexpr int LDB = 128 * 2 + 16;
  constexpr int PLANE = NOUT * LDB;
  __shared__ char lds[2 * PLANE];

  const int tid = threadIdx.x;
  for (int u = tid; u < 2 * NOUT * 16; u += 256) {
    const int plane = u / (NOUT * 16);
    const int v = u % (NOUT * 16);
    const int nrow = v >> 4, seg = v & 15;
    const short* src = plane ? WtL : WtH;
    const float4 d = *(const float4*)&src[nrow * 128 + seg * 8];
    *(float4*)&lds[plane * PLANE + nrow * LDB + seg * 16] = d;
  }
  __syncthreads();

  const int lane = tid & 63;
  const int wv = tid >> 6;
  const int li = lane & 15;
  const int kg = lane >> 4;

  float bv[NT];
#pragma unroll
  for (int t = 0; t < NT; ++t) bv[t] = bias[t * 16 + li];

  for (int tile = blockIdx.x; tile < ntiles; tile += gridDim.x) {
    const int row = tile * 64 + wv * 16 + li;
    const int rowc = (row < nrows) ? row : (nrows - 1);
    const float* xrow = X + (size_t)rowc * 128;

    f32x4 acc[NT];
#pragma unroll
    for (int t = 0; t < NT; ++t) acc[t] = (f32x4){0.f, 0.f, 0.f, 0.f};

#pragma unroll
    for (int c = 0; c < 4; ++c) {
      const float4 p0 = *(const float4*)&xrow[c * 32 + kg * 8];
      const float4 p1 = *(const float4*)&xrow[c * 32 + kg * 8 + 4];
      float f[8] = {p0.x, p0.y, p0.z, p0.w, p1.x, p1.y, p1.z, p1.w};
      bf16x8 ah, al;
#pragma unroll
      for (int e = 0; e < 8; ++e) {
        const unsigned hb = rne_bf16(f[e]);
        const float hf = __uint_as_float(hb << 16);
        ah[e] = (short)hb;
        al[e] = (short)rne_bf16(f[e] - hf);
      }
      const int kb = c * 64 + kg * 16;
#pragma unroll
      for (int t = 0; t < NT; ++t) {
        const int boff = (t * 16 + li) * LDB + kb;
        const bf16x8 bh = *(const bf16x8*)&lds[boff];
        const bf16x8 bl = *(const bf16x8*)&lds[PLANE + boff];
        acc[t] = __builtin_amdgcn_mfma_f32_16x16x32_bf16(al, bh, acc[t], 0, 0, 0);
        acc[t] = __builtin_amdgcn_mfma_f32_16x16x32_bf16(ah, bl, acc[t], 0, 0, 0);
        acc[t] = __builtin_amdgcn_mfma_f32_16x16x32_bf16(ah, bh, acc[t], 0, 0, 0);
      }
    }

    const int orow = tile * 64 + wv * 16 + kg * 4;
#pragma unroll
    for (int t = 0; t < NT; ++t) {
      const int col = t * 16 + li;
#pragma unroll
      for (int r = 0; r < 4; ++r) {
        const int rr = orow + r;
        if (rr < nrows) {
          const float o = fmaxf(acc[t][r] + bv[t], 0.f);
          const unsigned hb = rne_bf16(o);
          const float hf = __uint_as_float(hb << 16);
          Yh[(size_t)rr * 128 + col] = (short)hb;
          Yl[(size_t)rr * 128 + col] = (short)rne_bf16(o - hf);
        }
      }
    }
  }
}

// ---------------- GEMM B (bf16-plane X): Y = X@W + b (fp32 out) -------------
template <int NOUT>
__global__ __launch_bounds__(256, 2) void gemm_pl_kernel(
    const short* __restrict__ Xh, const short* __restrict__ Xl,
    const short* __restrict__ WtH, const short* __restrict__ WtL,
    const float* __restrict__ bias, float* __restrict__ Y, int nrows,
    int ntiles) {
  constexpr int NT = NOUT / 16;
  constexpr int LDB = 128 * 2 + 16;
  constexpr int PLANE = NOUT * LDB;
  __shared__ char lds[2 * PLANE];

  const int tid = threadIdx.x;
  for (int u = tid; u < 2 * NOUT * 16; u += 256) {
    const int plane = u / (NOUT * 16);
    const int v = u % (NOUT * 16);
    const int nrow = v >> 4, seg = v & 15;
    const short* src = plane ? WtL : WtH;
    const float4 d = *(const float4*)&src[nrow * 128 + seg * 8];
    *(float4*)&lds[plane * PLANE + nrow * LDB + seg * 16] = d;
  }
  __syncthreads();

  const int lane = tid & 63;
  const int wv = tid >> 6;
  const int li = lane & 15;
  const int kg = lane >> 4;

  float bv[NT];
#pragma unroll
  for (int t = 0; t < NT; ++t) bv[t] = bias[t * 16 + li];

  for (int tile = blockIdx.x; tile < ntiles; tile += gridDim.x) {
    const int row = tile * 64 + wv * 16 + li;
    const int rowc = (row < nrows) ? row : (nrows - 1);
    const short* xh = Xh + (size_t)rowc * 128;
    const short* xl = Xl + (size_t)rowc * 128;

    f32x4 acc[NT];
#pragma unroll
    for (int t = 0; t < NT; ++t) acc[t] = (f32x4){0.f, 0.f, 0.f, 0.f};

#pragma unroll
    for (int c = 0; c < 4; ++c) {
      const bf16x8 ah = *(const bf16x8*)&xh[c * 32 + kg * 8];
      const bf16x8 al = *(const bf16x8*)&xl[c * 32 + kg * 8];
      const int kb = c * 64 + kg * 16;
#pragma unroll
      for (int t = 0; t < NT; ++t) {
        const int boff = (t * 16 + li) * LDB + kb;
        const bf16x8 bh = *(const bf16x8*)&lds[boff];
        const bf16x8 bl = *(const bf16x8*)&lds[PLANE + boff];
        acc[t] = __builtin_amdgcn_mfma_f32_16x16x32_bf16(al, bh, acc[t], 0, 0, 0);
        acc[t] = __builtin_amdgcn_mfma_f32_16x16x32_bf16(ah, bl, acc[t], 0, 0, 0);
        acc[t] = __builtin_amdgcn_mfma_f32_16x16x32_bf16(ah, bh, acc[t], 0, 0, 0);
      }
    }

    const int orow = tile * 64 + wv * 16 + kg * 4;
#pragma unroll
    for (int t = 0; t < NT; ++t) {
      const int col = t * 16 + li;
#pragma unroll
      for (int r = 0; r < 4; ++r) {
        const int rr = orow + r;
        if (rr < nrows) Y[(size_t)rr * NOUT + col] = acc[t][r] + bv[t];
      }
    }
  }
}

// ---------------- MaxK: radix-select -> (mask, ordered vals) + dense fp32 ---
// sp2[row*64 + j] = (val[j], val[j+64]) fp32, zeros where unselected.
__global__ __launch_bounds__(256) void maxk_kernel(
    const float* __restrict__ T, ulonglong2* __restrict__ Ms,
    float* __restrict__ Vs, float2* __restrict__ sp2, int nrows) {
  const int lane = threadIdx.x & 63;
  const int wid = threadIdx.x >> 6;
  const unsigned long long below = ((unsigned long long)1 << lane) - 1;

  for (int row = blockIdx.x * 4 + wid; row < nrows; row += gridDim.x * 4) {
    const float o0 = T[(size_t)row * 128 + lane];
    const float o1 = T[(size_t)row * 128 + 64 + lane];
    const unsigned u0 = __float_as_uint(o0);
    const unsigned u1 = __float_as_uint(o1);
    const unsigned k0 = u0 ^ (((unsigned)((int)u0 >> 31)) | 0x80000000u);
    const unsigned k1 = u1 ^ (((unsigned)((int)u1 >> 31)) | 0x80000000u);

    unsigned P = 0;
    int kth = 16;
#pragma unroll
    for (int b = 31; b >= 0; --b) {
      const unsigned long long ball0 = __ballot(((k0 ^ P) >> b) == 1u);
      const unsigned long long ball1 = __ballot(((k1 ^ P) >> b) == 1u);
      const int c = __popcll(ball0) + __popcll(ball1);
      if (c >= kth)
        P |= (1u << b);
      else
        kth -= c;
    }
    const bool gt0 = k0 > P, gt1 = k1 > P;
    const unsigned long long g0 = __ballot(gt0);
    const unsigned long long g1 = __ballot(gt1);
    const int need = 16 - __popcll(g0) - __popcll(g1);
    const unsigned long long e0 = __ballot(k0 == P);
    const unsigned long long e1 = __ballot(k1 == P);
    const int need1 = need - __popcll(e0);
    const bool s0 = gt0 || (((e0 >> lane) & 1) &&
                            ((int)__popcll(e0 & below) < need));
    const bool s1 = gt1 || (((e1 >> lane) & 1) &&
                            ((int)__popcll(e1 & below) < need1));
    const unsigned long long m0 = __ballot(s0);
    const unsigned long long m1 = __ballot(s1);

    if (lane == 0) Ms[row] = make_ulonglong2(m0, m1);
    if (s0) Vs[(size_t)row * 16 + __popcll(m0 & below)] = o0;
    if (s1) Vs[(size_t)row * 16 + __popcll(m0) + __popcll(m1 & below)] = o1;
    sp2[(size_t)row * 64 + lane] = make_float2(s0 ? o0 : 0.f, s1 ? o1 : 0.f);
  }
}

// ---------------- CSR build v2: two-level binning ---------------------------
__global__ __launch_bounds__(256) void bhist_kernel(const int* __restrict__ dst,
                                                    int* __restrict__ BC,
                                                    int E) {
  __shared__ int bh[NBUK];
  for (int i = threadIdx.x; i < NBUK; i += 256) bh[i] = 0;
  __syncthreads();
  const int stride = gridDim.x * 256;
  for (int e = blockIdx.x * 256 + threadIdx.x; e < E; e += stride)
    atomicAdd(&bh[dst[e] >> BSHIFT], 1);
  __syncthreads();
  for (int i = threadIdx.x; i < NBUK; i += 256)
    if (bh[i]) atomicAdd(&BC[i], bh[i]);
}

__global__ __launch_bounds__(NBUK) void bscan_kernel(
    const int* __restrict__ BC, int* __restrict__ bases,
    int* __restrict__ bcur, int* __restrict__ rs, int n, int E) {
  __shared__ int sc[NBUK];
  const int t = threadIdx.x;
  const int c = BC[t];
  sc[t] = c;
  __syncthreads();
  for (int st = 1; st < NBUK; st <<= 1) {
    const int v = sc[t];
    const int u = (t >= st) ? sc[t - st] : 0;
    __syncthreads();
    sc[t] = v + u;
    __syncthreads();
  }
  const int excl = sc[t] - c;
  bases[t] = excl;
  bcur[t] = excl;
  if (t == 0) rs[n] = E;
}

__global__ __launch_bounds__(256) void bin_kernel(
    const int* __restrict__ src, const int* __restrict__ dst,
    int* __restrict__ bcur, uint2* __restrict__ binned, int E, int chunk) {
  __shared__ int cnt[NBUK], off[NBUK], gbase[NBUK];
  __shared__ unsigned short bktof[4096];
  __shared__ uint2 buf[4096];
  const int t = threadIdx.x;
  const int beg = blockIdx.x * chunk;
  const int m = min(chunk, E - beg);
  if (m <= 0) return;

  for (int i = t; i < NBUK; i += 256) cnt[i] = 0;
  __syncthreads();

  int d[16], s[16], lp[16], bk[16];
#pragma unroll
  for (int i = 0; i < 16; ++i) {
    const int j = i * 256 + t;
    if (j < m) {
      d[i] = dst[beg + j];
      s[i] = src[beg + j];
      bk[i] = d[i] >> BSHIFT;
      lp[i] = atomicAdd(&cnt[bk[i]], 1);
    } else {
      bk[i] = -1;
    }
  }
  __syncthreads();

  for (int i = t; i < NBUK; i += 256) off[i] = cnt[i];
  __syncthreads();
  for (int st = 1; st < NBUK; st <<= 1) {
    int v0, v1, u0, u1;
    {
      const int i0 = t, i1 = t + 256;
      v0 = off[i0]; u0 = (i0 >= st) ? off[i0 - st] : 0;
      v1 = off[i1]; u1 = (i1 >= st) ? off[i1 - st] : 0;
    }
    __syncthreads();
    off[t] = v0 + u0;
    off[t + 256] = v1 + u1;
    __syncthreads();
  }

  for (int i = t; i < NBUK; i += 256) {
    const int c = cnt[i];
    if (c > 0) {
      gbase[i] = atomicAdd(&bcur[i], c);
      const int e0 = off[i] - c;
      for (int k = 0; k < c; ++k) bktof[e0 + k] = (unsigned short)i;
    }
  }
  __syncthreads();

#pragma unroll
  for (int i = 0; i < 16; ++i) {
    if (bk[i] >= 0) {
      buf[(off[bk[i]] - cnt[bk[i]]) + lp[i]] =
          make_uint2((unsigned)d[i], (unsigned)s[i]);
    }
  }
  __syncthreads();

  for (int j = t; j < m; j += 256) {
    const int b = bktof[j];
    const int e0 = off[b] - cnt[b];
    binned[gbase[b] + (j - e0)] = buf[j];
  }
}

__global__ __launch_bounds__(256) void bbuild_kernel(
    const int* __restrict__ bases, const int* __restrict__ BC,
    const uint2* __restrict__ binned, int* __restrict__ rs,
    int* __restrict__ csr_src, int n) {
  __shared__ int nd[256], sc[256], cur[256];
  const int b = blockIdx.x;
  const int t = threadIdx.x;
  const int base = bases[b];
  const int count = BC[b];
  const int node0 = b << BSHIFT;

  nd[t] = 0;
  __syncthreads();
  for (int i = t; i < count; i += 256)
    atomicAdd(&nd[binned[base + i].x & 255], 1);
  __syncthreads();

  sc[t] = nd[t];
  __syncthreads();
  for (int st = 1; st < 256; st <<= 1) {
    const int v = sc[t];
    const int u = (t >= st) ? sc[t - st] : 0;
    __syncthreads();
    sc[t] = v + u;
    __syncthreads();
  }
  const int excl = sc[t] - nd[t];
  cur[t] = excl;
  if (node0 + t < n) rs[node0 + t] = base + excl;
  __syncthreads();

  for (int i = t; i < count; i += 256) {
    const uint2 p = binned[base + i];
    const int pos = atomicAdd(&cur[p.x & 255], 1);
    csr_src[base + pos] = (int)p.y;
  }
}

// ---------------- Gather v2 (rank-select, fp32 vals) ------------------------
__global__ __launch_bounds__(256) void gather2_kernel(
    const int* __restrict__ rs, const int* __restrict__ csr_src,
    const ulonglong2* __restrict__ Ms, const float* __restrict__ Vs,
    const float* __restrict__ eps_p, short* __restrict__ Ah,
    short* __restrict__ Al, int nrows) {
  __shared__ __align__(16) float sv[4][16][16];
  __shared__ ulonglong2 sm[4][16];
  const int lane = threadIdx.x & 63;
  const int wid = threadIdx.x >> 6;
  const float e1 = 1.0f + *eps_p;
  const unsigned long long below = ((unsigned long long)1 << lane) - 1;
  const int ee = lane >> 2;
  const int q = lane & 3;

  for (int r = blockIdx.x * 4 + wid; r < nrows; r += gridDim.x * 4) {
    float acc0 = 0.f, acc1 = 0.f;
    const int beg = rs[r], end = rs[r + 1];

    for (int base = beg; base < end; base += 16) {
      const int cnt = min(16, end - base);
      if (ee < cnt) {
        const int s = csr_src[base + ee];
        if (q == 0) sm[wid][ee] = Ms[s];
        const float4 v = *(const float4*)&Vs[(size_t)s * 16 + q * 4];
        *(float4*)&sv[wid][ee][q * 4] = v;
      }
      for (int e = 0; e < cnt; ++e) {
        const ulonglong2 mm = sm[wid][e];
        if ((mm.x >> lane) & 1)
          acc0 += sv[wid][e][__popcll(mm.x & below)];
        if ((mm.y >> lane) & 1)
          acc1 += sv[wid][e][__popcll(mm.x) + __popcll(mm.y & below)];
      }
    }

    {
      const ulonglong2 mr = Ms[r];
      if ((mr.x >> lane) & 1)
        acc0 += e1 * Vs[(size_t)r * 16 + __popcll(mr.x & below)];
      if ((mr.y >> lane) & 1)
        acc1 += e1 * Vs[(size_t)r * 16 + __popcll(mr.x) + __popcll(mr.y & below)];
    }

    const unsigned h0 = rne_bf16(acc0);
    const unsigned h1 = rne_bf16(acc1);
    Ah[(size_t)r * 128 + lane] = (short)h0;
    Ah[(size_t)r * 128 + 64 + lane] = (short)h1;
    Al[(size_t)r * 128 + lane] =
        (short)rne_bf16(acc0 - __uint_as_float(h0 << 16));
    Al[(size_t)r * 128 + 64 + lane] =
        (short)rne_bf16(acc1 - __uint_as_float(h1 << 16));
  }
}

// ---------------- Gather v5: dense fp32 float2 rows (exact, load-bound) -----
__global__ __launch_bounds__(256) void gather5_kernel(
    const int* __restrict__ rs, const int* __restrict__ csr_src,
    const float2* __restrict__ sp2, const float* __restrict__ eps_p,
    short* __restrict__ Ah, short* __restrict__ Al, int nrows) {
  const int lane = threadIdx.x & 63;
  const int wid = threadIdx.x >> 6;
  const float e1 = 1.0f + *eps_p;

  for (int r = blockIdx.x * 4 + wid; r < nrows; r += gridDim.x * 4) {
    float acc0, acc1;
    {
      const float2 u = sp2[((size_t)r << 6) + lane];
      acc0 = e1 * u.x;
      acc1 = e1 * u.y;
    }

    const int beg = rs[r], end = rs[r + 1];
    for (int base = beg; base < end; base += 64) {
      const int cnt = min(64, end - base);
      const int es = (lane < cnt) ? csr_src[base + lane] : 0;
      int e = 0;
      for (; e + 4 <= cnt; e += 4) {
        const int s0 = __shfl(es, e + 0);
        const int s1 = __shfl(es, e + 1);
        const int s2 = __shfl(es, e + 2);
        const int s3 = __shfl(es, e + 3);
        const float2 q0 = sp2[((size_t)s0 << 6) + lane];
        const float2 q1 = sp2[((size_t)s1 << 6) + lane];
        const float2 q2 = sp2[((size_t)s2 << 6) + lane];
        const float2 q3 = sp2[((size_t)s3 << 6) + lane];
        acc0 += q0.x; acc1 += q0.y;
        acc0 += q1.x; acc1 += q1.y;
        acc0 += q2.x; acc1 += q2.y;
        acc0 += q3.x; acc1 += q3.y;
      }
      for (; e < cnt; ++e) {
        const int s = __shfl(es, e);
        const float2 q = sp2[((size_t)s << 6) + lane];
        acc0 += q.x;
        acc1 += q.y;
      }
    }

    const unsigned h0 = rne_bf16(acc0);
    const unsigned h1 = rne_bf16(acc1);
    Ah[(size_t)r * 128 + lane] = (short)h0;
    Ah[(size_t)r * 128 + 64 + lane] = (short)h1;
    Al[(size_t)r * 128 + lane] =
        (short)rne_bf16(acc0 - __uint_as_float(h0 << 16));
    Al[(size_t)r * 128 + 64 + lane] =
        (short)rne_bf16(acc1 - __uint_as_float(h1 << 16));
  }
}

// ---------------------------------------------------------------------------
extern "C" void kernel_launch(void* const* d_in, const int* in_sizes, int n_in,
                              void* d_out, int out_size, void* d_ws,
                              size_t ws_size, hipStream_t stream) {
  const float* x = (const float*)d_in[0];
  const int* src = (const int*)d_in[1];
  const int* dst = (const int*)d_in[2];
  const float* W_in = (const float*)d_in[3];
  const float* b_in = (const float*)d_in[4];
  const float* W_lin = (const float*)d_in[5];
  const float* b_lin = (const float*)d_in[6];
  const float* eps = (const float*)d_in[7];
  const float* W_out = (const float*)d_in[8];
  const float* b_out = (const float*)d_in[9];
  float* out = (float*)d_out;

  const int n = in_sizes[0] / 128;
  const int E = in_sizes[1];

  char* w = (char*)d_ws;
  float* B = (float*)w;               w += (size_t)n * 128 * 4;
  ulonglong2* Ms = (ulonglong2*)w;    w += (size_t)n * 16;
  float* Vs = (float*)w;              w += (size_t)n * 16 * 4;
  float2* sp2 = (float2*)w;           w += (size_t)n * 64 * 8;
  int* rs = (int*)w;                  w += (size_t)(n + 1) * 4;
  int* csr_src = (int*)w;             w += (size_t)E * 4;
  uint2* binned = (uint2*)w;          w += (size_t)E * 8;
  int* BC = (int*)w;                  w += NBUK * 4;
  int* bases = (int*)w;               w += NBUK * 4;
  int* bcur = (int*)w;                w += NBUK * 4;
  short* wtAll = (short*)w;           w += (size_t)114688 * 2;
  short* Ah = (short*)w;              w += (size_t)n * 128 * 2;
  short* Al = (short*)w;              w += (size_t)n * 128 * 2;

  short* wtIn = wtAll;
  short* wtL0 = wtAll + 32768;
  short* wtL1 = wtAll + 65536;
  short* wtOut = wtAll + 98304;

  const int gtiles = (n + 63) / 64;
  const int nbuk_eff = (n + 255) >> BSHIFT;
  const int chunk = 4000;
  const int cblocks = (E + chunk - 1) / chunk;
  const dim3 blk(256);

  // ---- CSR build ----
  hipMemsetAsync(BC, 0, NBUK * 4, stream);
  bhist_kernel<<<256, blk, 0, stream>>>(dst, BC, E);
  bscan_kernel<<<1, NBUK, 0, stream>>>(BC, bases, bcur, rs, n, E);
  bin_kernel<<<cblocks, blk, 0, stream>>>(src, dst, bcur, binned, E, chunk);
  bbuild_kernel<<<nbuk_eff, blk, 0, stream>>>(bases, BC, binned, rs, csr_src,
                                              n);

  // ---- weights -> hi/lo bf16 ----
  wt_build_all_kernel<<<(57344 + 255) / 256, blk, 0, stream>>>(W_in, W_lin,
                                                               W_out, wtAll);

  // ---- h = relu(x @ W_in + b_in) -> planes ----
  gemm_in_kernel<<<512, blk, 0, stream>>>(x, wtIn, wtIn + 16384, b_in, Ah, Al,
                                          n, gtiles);

  for (int l = 0; l < 2; ++l) {
    short* wt = l ? wtL1 : wtL0;
    gemm_pl_kernel<128><<<512, blk, 0, stream>>>(
        Ah, Al, wt, wt + 16384, b_lin + (size_t)l * 128, B, n, gtiles);
    maxk_kernel<<<2048, blk, 0, stream>>>(B, Ms, Vs, sp2, n);
    if (l == 0) {
      gather2_kernel<<<2048, blk, 0, stream>>>(rs, csr_src, Ms, Vs, eps + l,
                                               Ah, Al, n);
    } else {
      gather5_kernel<<<2048, blk, 0, stream>>>(rs, csr_src, sp2, eps + l, Ah,
                                               Al, n);
    }
  }

  gemm_pl_kernel<64><<<512, blk, 0, stream>>>(Ah, Al, wtOut, wtOut + 8192,
                                              b_out, out, n, gtiles);
}

// Round 12
// 555.189 us; speedup vs baseline: 1.7055x; 1.1158x over previous
//
#include <hip/hip_runtime.h>
#include <cstdint>
#include <cstddef>

// ---------------------------------------------------------------------------
// MaxKGIN. R12: A/B verdict — gather5 (dense fp32) 127us LOSES to gather2
// (rank-select) 109us; revert to gather2 both layers, drop sp2.
// gemm_pl rebuilt for arithmetic intensity: 64 rows/wave (4 rowgroups), each
// W-fragment LDS read feeds 12 MFMAs (was 3) -> MFMA-bound, not LDS-bound.
// 256-row blocks, all co-resident. gemm_in unchanged. CSR: two-level binning.
// ---------------------------------------------------------------------------

typedef __attribute__((ext_vector_type(8))) short bf16x8;
typedef __attribute__((ext_vector_type(4))) float f32x4;

#define BSHIFT 8
#define NBUK 512  // covers dst>>8 for n <= 131072

__device__ __forceinline__ unsigned rne_bf16(float v) {
  unsigned u = __float_as_uint(v);
  return (u + 0x7fffu + ((u >> 16) & 1u)) >> 16;
}

// ---------------- fused W^T build: all 4 weights -> hi/lo bf16 --------------
__global__ __launch_bounds__(256) void wt_build_all_kernel(
    const float* __restrict__ W_in, const float* __restrict__ W_lin,
    const float* __restrict__ W_out, short* __restrict__ out) {
  const int i = blockIdx.x * 256 + threadIdx.x;
  if (i >= 57344) return;
  const float* W;
  int nout, local;
  short* H;
  if (i < 16384) {
    W = W_in; nout = 128; local = i; H = out;
  } else if (i < 32768) {
    W = W_lin; nout = 128; local = i - 16384; H = out + 32768;
  } else if (i < 49152) {
    W = W_lin + 16384; nout = 128; local = i - 32768; H = out + 65536;
  } else {
    W = W_out; nout = 64; local = i - 49152; H = out + 98304;
  }
  const int nn = local >> 7, k = local & 127;
  const float v = W[k * nout + nn];
  const unsigned hb = rne_bf16(v);
  const float hf = __uint_as_float(hb << 16);
  const unsigned lb = rne_bf16(v - hf);
  H[local] = (short)hb;
  H[local + nout * 128] = (short)lb;
}

// ---------------- GEMM A (fp32 X): Yh/Yl = split(relu(X@W+b)) ---------------
__global__ __launch_bounds__(256, 2) void gemm_in_kernel(
    const float* __restrict__ X, const short* __restrict__ WtH,
    const short* __restrict__ WtL, const float* __restrict__ bias,
    short* __restrict__ Yh, short* __restrict__ Yl, int nrows, int ntiles) {
  constexpr int NOUT = 128;
  constexpr int NT = NOUT / 16;
  constexpr int LDB = 128 * 2 + 16;
  constexpr int PLANE = NOUT * LDB;
  __shared__ char lds[2 * PLANE];

  const int tid = threadIdx.x;
  for (int u = tid; u < 2 * NOUT * 16; u += 256) {
    const int plane = u / (NOUT * 16);
    const int v = u % (NOUT * 16);
    const int nrow = v >> 4, seg = v & 15;
    const short* src = plane ? WtL : WtH;
    const float4 d = *(const float4*)&src[nrow * 128 + seg * 8];
    *(float4*)&lds[plane * PLANE + nrow * LDB + seg * 16] = d;
  }
  __syncthreads();

  const int lane = tid & 63;
  const int wv = tid >> 6;
  const int li = lane & 15;
  const int kg = lane >> 4;

  float bv[NT];
#pragma unroll
  for (int t = 0; t < NT; ++t) bv[t] = bias[t * 16 + li];

  for (int tile = blockIdx.x; tile < ntiles; tile += gridDim.x) {
    const int row = tile * 64 + wv * 16 + li;
    const int rowc = (row < nrows) ? row : (nrows - 1);
    const float* xrow = X + (size_t)rowc * 128;

    f32x4 acc[NT];
#pragma unroll
    for (int t = 0; t < NT; ++t) acc[t] = (f32x4){0.f, 0.f, 0.f, 0.f};

#pragma unroll
    for (int c = 0; c < 4; ++c) {
      const float4 p0 = *(const float4*)&xrow[c * 32 + kg * 8];
      const float4 p1 = *(const float4*)&xrow[c * 32 + kg * 8 + 4];
      float f[8] = {p0.x, p0.y, p0.z, p0.w, p1.x, p1.y, p1.z, p1.w};
      bf16x8 ah, al;
#pragma unroll
      for (int e = 0; e < 8; ++e) {
        const unsigned hb = rne_bf16(f[e]);
        const float hf = __uint_as_float(hb << 16);
        ah[e] = (short)hb;
        al[e] = (short)rne_bf16(f[e] - hf);
      }
      const int kb = c * 64 + kg * 16;
#pragma unroll
      for (int t = 0; t < NT; ++t) {
        const int boff = (t * 16 + li) * LDB + kb;
        const bf16x8 bh = *(const bf16x8*)&lds[boff];
        const bf16x8 bl = *(const bf16x8*)&lds[PLANE + boff];
        acc[t] = __builtin_amdgcn_mfma_f32_16x16x32_bf16(al, bh, acc[t], 0, 0, 0);
        acc[t] = __builtin_amdgcn_mfma_f32_16x16x32_bf16(ah, bl, acc[t], 0, 0, 0);
        acc[t] = __builtin_amdgcn_mfma_f32_16x16x32_bf16(ah, bh, acc[t], 0, 0, 0);
      }
    }

    const int orow = tile * 64 + wv * 16 + kg * 4;
#pragma unroll
    for (int t = 0; t < NT; ++t) {
      const int col = t * 16 + li;
#pragma unroll
      for (int r = 0; r < 4; ++r) {
        const int rr = orow + r;
        if (rr < nrows) {
          const float o = fmaxf(acc[t][r] + bv[t], 0.f);
          const unsigned hb = rne_bf16(o);
          const float hf = __uint_as_float(hb << 16);
          Yh[(size_t)rr * 128 + col] = (short)hb;
          Yl[(size_t)rr * 128 + col] = (short)rne_bf16(o - hf);
        }
      }
    }
  }
}

// ---------------- GEMM B v2 (bf16-plane X): 64 rows/wave, high intensity ----
// Each W-fragment ds_read feeds 12 MFMAs (4 rowgroups x 3 products).
template <int NOUT>
__global__ __launch_bounds__(256, 2) void gemm_pl_kernel(
    const short* __restrict__ Xh, const short* __restrict__ Xl,
    const short* __restrict__ WtH, const short* __restrict__ WtL,
    const float* __restrict__ bias, float* __restrict__ Y, int nrows,
    int ntiles) {
  constexpr int NT = NOUT / 16;
  constexpr int LDB = 128 * 2 + 16;
  constexpr int PLANE = NOUT * LDB;
  __shared__ char lds[2 * PLANE];

  const int tid = threadIdx.x;
  for (int u = tid; u < 2 * NOUT * 16; u += 256) {
    const int plane = u / (NOUT * 16);
    const int v = u % (NOUT * 16);
    const int nrow = v >> 4, seg = v & 15;
    const short* src = plane ? WtL : WtH;
    const float4 d = *(const float4*)&src[nrow * 128 + seg * 8];
    *(float4*)&lds[plane * PLANE + nrow * LDB + seg * 16] = d;
  }
  __syncthreads();

  const int lane = tid & 63;
  const int wv = tid >> 6;
  const int li = lane & 15;
  const int kg = lane >> 4;

  float bv[NT];
#pragma unroll
  for (int t = 0; t < NT; ++t) bv[t] = bias[t * 16 + li];

  for (int tile = blockIdx.x; tile < ntiles; tile += gridDim.x) {
    const int rowbase = tile * 256 + wv * 64;

    f32x4 acc[4][NT];
#pragma unroll
    for (int rg = 0; rg < 4; ++rg)
#pragma unroll
      for (int t = 0; t < NT; ++t) acc[rg][t] = (f32x4){0.f, 0.f, 0.f, 0.f};

#pragma unroll
    for (int c = 0; c < 4; ++c) {
      bf16x8 ah[4], al[4];
#pragma unroll
      for (int rg = 0; rg < 4; ++rg) {
        const int row = rowbase + rg * 16 + li;
        const int rowc = (row < nrows) ? row : (nrows - 1);
        ah[rg] = *(const bf16x8*)&Xh[(size_t)rowc * 128 + c * 32 + kg * 8];
        al[rg] = *(const bf16x8*)&Xl[(size_t)rowc * 128 + c * 32 + kg * 8];
      }
      const int kb = c * 64 + kg * 16;
#pragma unroll
      for (int t = 0; t < NT; ++t) {
        const int boff = (t * 16 + li) * LDB + kb;
        const bf16x8 bh = *(const bf16x8*)&lds[boff];
        const bf16x8 bl = *(const bf16x8*)&lds[PLANE + boff];
#pragma unroll
        for (int rg = 0; rg < 4; ++rg) {
          acc[rg][t] =
              __builtin_amdgcn_mfma_f32_16x16x32_bf16(al[rg], bh, acc[rg][t], 0, 0, 0);
          acc[rg][t] =
              __builtin_amdgcn_mfma_f32_16x16x32_bf16(ah[rg], bl, acc[rg][t], 0, 0, 0);
          acc[rg][t] =
              __builtin_amdgcn_mfma_f32_16x16x32_bf16(ah[rg], bh, acc[rg][t], 0, 0, 0);
        }
      }
    }

#pragma unroll
    for (int rg = 0; rg < 4; ++rg) {
      const int orow = rowbase + rg * 16 + kg * 4;
#pragma unroll
      for (int t = 0; t < NT; ++t) {
        const int col = t * 16 + li;
#pragma unroll
        for (int r = 0; r < 4; ++r) {
          const int rr = orow + r;
          if (rr < nrows) Y[(size_t)rr * NOUT + col] = acc[rg][t][r] + bv[t];
        }
      }
    }
  }
}

// ---------------- MaxK: radix-select top-16 -> (mask, col-ordered vals) -----
__global__ __launch_bounds__(256) void maxk_kernel(
    const float* __restrict__ T, ulonglong2* __restrict__ Ms,
    float* __restrict__ Vs, int nrows) {
  const int lane = threadIdx.x & 63;
  const int wid = threadIdx.x >> 6;
  const unsigned long long below = ((unsigned long long)1 << lane) - 1;

  for (int row = blockIdx.x * 4 + wid; row < nrows; row += gridDim.x * 4) {
    const float o0 = T[(size_t)row * 128 + lane];
    const float o1 = T[(size_t)row * 128 + 64 + lane];
    const unsigned u0 = __float_as_uint(o0);
    const unsigned u1 = __float_as_uint(o1);
    const unsigned k0 = u0 ^ (((unsigned)((int)u0 >> 31)) | 0x80000000u);
    const unsigned k1 = u1 ^ (((unsigned)((int)u1 >> 31)) | 0x80000000u);

    unsigned P = 0;
    int kth = 16;
#pragma unroll
    for (int b = 31; b >= 0; --b) {
      const unsigned long long ball0 = __ballot(((k0 ^ P) >> b) == 1u);
      const unsigned long long ball1 = __ballot(((k1 ^ P) >> b) == 1u);
      const int c = __popcll(ball0) + __popcll(ball1);
      if (c >= kth)
        P |= (1u << b);
      else
        kth -= c;
    }
    const bool gt0 = k0 > P, gt1 = k1 > P;
    const unsigned long long g0 = __ballot(gt0);
    const unsigned long long g1 = __ballot(gt1);
    const int need = 16 - __popcll(g0) - __popcll(g1);
    const unsigned long long e0 = __ballot(k0 == P);
    const unsigned long long e1 = __ballot(k1 == P);
    const int need1 = need - __popcll(e0);
    const bool s0 = gt0 || (((e0 >> lane) & 1) &&
                            ((int)__popcll(e0 & below) < need));
    const bool s1 = gt1 || (((e1 >> lane) & 1) &&
                            ((int)__popcll(e1 & below) < need1));
    const unsigned long long m0 = __ballot(s0);
    const unsigned long long m1 = __ballot(s1);

    if (lane == 0) Ms[row] = make_ulonglong2(m0, m1);
    if (s0) Vs[(size_t)row * 16 + __popcll(m0 & below)] = o0;
    if (s1) Vs[(size_t)row * 16 + __popcll(m0) + __popcll(m1 & below)] = o1;
  }
}

// ---------------- CSR build v2: two-level binning ---------------------------
__global__ __launch_bounds__(256) void bhist_kernel(const int* __restrict__ dst,
                                                    int* __restrict__ BC,
                                                    int E) {
  __shared__ int bh[NBUK];
  for (int i = threadIdx.x; i < NBUK; i += 256) bh[i] = 0;
  __syncthreads();
  const int stride = gridDim.x * 256;
  for (int e = blockIdx.x * 256 + threadIdx.x; e < E; e += stride)
    atomicAdd(&bh[dst[e] >> BSHIFT], 1);
  __syncthreads();
  for (int i = threadIdx.x; i < NBUK; i += 256)
    if (bh[i]) atomicAdd(&BC[i], bh[i]);
}

__global__ __launch_bounds__(NBUK) void bscan_kernel(
    const int* __restrict__ BC, int* __restrict__ bases,
    int* __restrict__ bcur, int* __restrict__ rs, int n, int E) {
  __shared__ int sc[NBUK];
  const int t = threadIdx.x;
  const int c = BC[t];
  sc[t] = c;
  __syncthreads();
  for (int st = 1; st < NBUK; st <<= 1) {
    const int v = sc[t];
    const int u = (t >= st) ? sc[t - st] : 0;
    __syncthreads();
    sc[t] = v + u;
    __syncthreads();
  }
  const int excl = sc[t] - c;
  bases[t] = excl;
  bcur[t] = excl;
  if (t == 0) rs[n] = E;
}

__global__ __launch_bounds__(256) void bin_kernel(
    const int* __restrict__ src, const int* __restrict__ dst,
    int* __restrict__ bcur, uint2* __restrict__ binned, int E, int chunk) {
  __shared__ int cnt[NBUK], off[NBUK], gbase[NBUK];
  __shared__ unsigned short bktof[4096];
  __shared__ uint2 buf[4096];
  const int t = threadIdx.x;
  const int beg = blockIdx.x * chunk;
  const int m = min(chunk, E - beg);
  if (m <= 0) return;

  for (int i = t; i < NBUK; i += 256) cnt[i] = 0;
  __syncthreads();

  int d[16], s[16], lp[16], bk[16];
#pragma unroll
  for (int i = 0; i < 16; ++i) {
    const int j = i * 256 + t;
    if (j < m) {
      d[i] = dst[beg + j];
      s[i] = src[beg + j];
      bk[i] = d[i] >> BSHIFT;
      lp[i] = atomicAdd(&cnt[bk[i]], 1);
    } else {
      bk[i] = -1;
    }
  }
  __syncthreads();

  for (int i = t; i < NBUK; i += 256) off[i] = cnt[i];
  __syncthreads();
  for (int st = 1; st < NBUK; st <<= 1) {
    int v0, v1, u0, u1;
    {
      const int i0 = t, i1 = t + 256;
      v0 = off[i0]; u0 = (i0 >= st) ? off[i0 - st] : 0;
      v1 = off[i1]; u1 = (i1 >= st) ? off[i1 - st] : 0;
    }
    __syncthreads();
    off[t] = v0 + u0;
    off[t + 256] = v1 + u1;
    __syncthreads();
  }

  for (int i = t; i < NBUK; i += 256) {
    const int c = cnt[i];
    if (c > 0) {
      gbase[i] = atomicAdd(&bcur[i], c);
      const int e0 = off[i] - c;
      for (int k = 0; k < c; ++k) bktof[e0 + k] = (unsigned short)i;
    }
  }
  __syncthreads();

#pragma unroll
  for (int i = 0; i < 16; ++i) {
    if (bk[i] >= 0) {
      buf[(off[bk[i]] - cnt[bk[i]]) + lp[i]] =
          make_uint2((unsigned)d[i], (unsigned)s[i]);
    }
  }
  __syncthreads();

  for (int j = t; j < m; j += 256) {
    const int b = bktof[j];
    const int e0 = off[b] - cnt[b];
    binned[gbase[b] + (j - e0)] = buf[j];
  }
}

__global__ __launch_bounds__(256) void bbuild_kernel(
    const int* __restrict__ bases, const int* __restrict__ BC,
    const uint2* __restrict__ binned, int* __restrict__ rs,
    int* __restrict__ csr_src, int n) {
  __shared__ int nd[256], sc[256], cur[256];
  const int b = blockIdx.x;
  const int t = threadIdx.x;
  const int base = bases[b];
  const int count = BC[b];
  const int node0 = b << BSHIFT;

  nd[t] = 0;
  __syncthreads();
  for (int i = t; i < count; i += 256)
    atomicAdd(&nd[binned[base + i].x & 255], 1);
  __syncthreads();

  sc[t] = nd[t];
  __syncthreads();
  for (int st = 1; st < 256; st <<= 1) {
    const int v = sc[t];
    const int u = (t >= st) ? sc[t - st] : 0;
    __syncthreads();
    sc[t] = v + u;
    __syncthreads();
  }
  const int excl = sc[t] - nd[t];
  cur[t] = excl;
  if (node0 + t < n) rs[node0 + t] = base + excl;
  __syncthreads();

  for (int i = t; i < count; i += 256) {
    const uint2 p = binned[base + i];
    const int pos = atomicAdd(&cur[p.x & 255], 1);
    csr_src[base + pos] = (int)p.y;
  }
}

// ---------------- Gather v2 (rank-select, fp32 vals) ------------------------
__global__ __launch_bounds__(256) void gather2_kernel(
    const int* __restrict__ rs, const int* __restrict__ csr_src,
    const ulonglong2* __restrict__ Ms, const float* __restrict__ Vs,
    const float* __restrict__ eps_p, short* __restrict__ Ah,
    short* __restrict__ Al, int nrows) {
  __shared__ __align__(16) float sv[4][16][16];
  __shared__ ulonglong2 sm[4][16];
  const int lane = threadIdx.x & 63;
  const int wid = threadIdx.x >> 6;
  const float e1 = 1.0f + *eps_p;
  const unsigned long long below = ((unsigned long long)1 << lane) - 1;
  const int ee = lane >> 2;
  const int q = lane & 3;

  for (int r = blockIdx.x * 4 + wid; r < nrows; r += gridDim.x * 4) {
    float acc0 = 0.f, acc1 = 0.f;
    const int beg = rs[r], end = rs[r + 1];

    for (int base = beg; base < end; base += 16) {
      const int cnt = min(16, end - base);
      if (ee < cnt) {
        const int s = csr_src[base + ee];
        if (q == 0) sm[wid][ee] = Ms[s];
        const float4 v = *(const float4*)&Vs[(size_t)s * 16 + q * 4];
        *(float4*)&sv[wid][ee][q * 4] = v;
      }
      for (int e = 0; e < cnt; ++e) {
        const ulonglong2 mm = sm[wid][e];
        if ((mm.x >> lane) & 1)
          acc0 += sv[wid][e][__popcll(mm.x & below)];
        if ((mm.y >> lane) & 1)
          acc1 += sv[wid][e][__popcll(mm.x) + __popcll(mm.y & below)];
      }
    }

    {
      const ulonglong2 mr = Ms[r];
      if ((mr.x >> lane) & 1)
        acc0 += e1 * Vs[(size_t)r * 16 + __popcll(mr.x & below)];
      if ((mr.y >> lane) & 1)
        acc1 += e1 * Vs[(size_t)r * 16 + __popcll(mr.x) + __popcll(mr.y & below)];
    }

    const unsigned h0 = rne_bf16(acc0);
    const unsigned h1 = rne_bf16(acc1);
    Ah[(size_t)r * 128 + lane] = (short)h0;
    Ah[(size_t)r * 128 + 64 + lane] = (short)h1;
    Al[(size_t)r * 128 + lane] =
        (short)rne_bf16(acc0 - __uint_as_float(h0 << 16));
    Al[(size_t)r * 128 + 64 + lane] =
        (short)rne_bf16(acc1 - __uint_as_float(h1 << 16));
  }
}

// ---------------------------------------------------------------------------
extern "C" void kernel_launch(void* const* d_in, const int* in_sizes, int n_in,
                              void* d_out, int out_size, void* d_ws,
                              size_t ws_size, hipStream_t stream) {
  const float* x = (const float*)d_in[0];
  const int* src = (const int*)d_in[1];
  const int* dst = (const int*)d_in[2];
  const float* W_in = (const float*)d_in[3];
  const float* b_in = (const float*)d_in[4];
  const float* W_lin = (const float*)d_in[5];
  const float* b_lin = (const float*)d_in[6];
  const float* eps = (const float*)d_in[7];
  const float* W_out = (const float*)d_in[8];
  const float* b_out = (const float*)d_in[9];
  float* out = (float*)d_out;

  const int n = in_sizes[0] / 128;
  const int E = in_sizes[1];

  char* w = (char*)d_ws;
  float* B = (float*)w;               w += (size_t)n * 128 * 4;
  ulonglong2* Ms = (ulonglong2*)w;    w += (size_t)n * 16;
  float* Vs = (float*)w;              w += (size_t)n * 16 * 4;
  int* rs = (int*)w;                  w += (size_t)(n + 1) * 4;
  int* csr_src = (int*)w;             w += (size_t)E * 4;
  uint2* binned = (uint2*)w;          w += (size_t)E * 8;
  int* BC = (int*)w;                  w += NBUK * 4;
  int* bases = (int*)w;               w += NBUK * 4;
  int* bcur = (int*)w;                w += NBUK * 4;
  short* wtAll = (short*)w;           w += (size_t)114688 * 2;
  short* Ah = (short*)w;              w += (size_t)n * 128 * 2;
  short* Al = (short*)w;              w += (size_t)n * 128 * 2;

  short* wtIn = wtAll;
  short* wtL0 = wtAll + 32768;
  short* wtL1 = wtAll + 65536;
  short* wtOut = wtAll + 98304;

  const int gtiles = (n + 63) / 64;        // gemm_in: 64-row tiles
  const int ptiles = (n + 255) / 256;      // gemm_pl: 256-row tiles
  const int nbuk_eff = (n + 255) >> BSHIFT;
  const int chunk = 4000;
  const int cblocks = (E + chunk - 1) / chunk;
  const dim3 blk(256);

  // ---- CSR build ----
  hipMemsetAsync(BC, 0, NBUK * 4, stream);
  bhist_kernel<<<256, blk, 0, stream>>>(dst, BC, E);
  bscan_kernel<<<1, NBUK, 0, stream>>>(BC, bases, bcur, rs, n, E);
  bin_kernel<<<cblocks, blk, 0, stream>>>(src, dst, bcur, binned, E, chunk);
  bbuild_kernel<<<nbuk_eff, blk, 0, stream>>>(bases, BC, binned, rs, csr_src,
                                              n);

  // ---- weights -> hi/lo bf16 ----
  wt_build_all_kernel<<<(57344 + 255) / 256, blk, 0, stream>>>(W_in, W_lin,
                                                               W_out, wtAll);

  // ---- h = relu(x @ W_in + b_in) -> planes ----
  gemm_in_kernel<<<512, blk, 0, stream>>>(x, wtIn, wtIn + 16384, b_in, Ah, Al,
                                          n, gtiles);

  for (int l = 0; l < 2; ++l) {
    short* wt = l ? wtL1 : wtL0;
    gemm_pl_kernel<128><<<ptiles, blk, 0, stream>>>(
        Ah, Al, wt, wt + 16384, b_lin + (size_t)l * 128, B, n, ptiles);
    maxk_kernel<<<2048, blk, 0, stream>>>(B, Ms, Vs, n);
    gather2_kernel<<<2048, blk, 0, stream>>>(rs, csr_src, Ms, Vs, eps + l, Ah,
                                             Al, n);
  }

  gemm_pl_kernel<64><<<ptiles, blk, 0, stream>>>(Ah, Al, wtOut, wtOut + 8192,
                                                 b_out, out, n, ptiles);
}

// Round 13
// 444.546 us; speedup vs baseline: 2.1299x; 1.2489x over previous
//
#include <hip/hip_runtime.h>
#include <cstdint>
#include <cstddef>

// ---------------------------------------------------------------------------
// MaxKGIN. R13: gather6 — LDS private-copy scatter. maxk emits (cols u8[16],
// vals f32[16]); 16 lanes/edge scatter directly into 4 per-group private LDS
// accumulator copies (no atomics: cols distinct within edge, copies disjoint
// across groups, DS in-order across iterations). ~4 LDS + 5 VALU per 4 edges
// vs gather2's ~80 VALU (was 109us, VALU 70%).
// GEMMs: gemm_in (64-row) + gemm_pl v2 (256-row, 12 MFMA per W-fragment).
// CSR: two-level binning. All else frozen from r12 (555us).
// ---------------------------------------------------------------------------

typedef __attribute__((ext_vector_type(8))) short bf16x8;
typedef __attribute__((ext_vector_type(4))) float f32x4;

#define BSHIFT 8
#define NBUK 512  // covers dst>>8 for n <= 131072

__device__ __forceinline__ unsigned rne_bf16(float v) {
  unsigned u = __float_as_uint(v);
  return (u + 0x7fffu + ((u >> 16) & 1u)) >> 16;
}

// ---------------- fused W^T build: all 4 weights -> hi/lo bf16 --------------
__global__ __launch_bounds__(256) void wt_build_all_kernel(
    const float* __restrict__ W_in, const float* __restrict__ W_lin,
    const float* __restrict__ W_out, short* __restrict__ out) {
  const int i = blockIdx.x * 256 + threadIdx.x;
  if (i >= 57344) return;
  const float* W;
  int nout, local;
  short* H;
  if (i < 16384) {
    W = W_in; nout = 128; local = i; H = out;
  } else if (i < 32768) {
    W = W_lin; nout = 128; local = i - 16384; H = out + 32768;
  } else if (i < 49152) {
    W = W_lin + 16384; nout = 128; local = i - 32768; H = out + 65536;
  } else {
    W = W_out; nout = 64; local = i - 49152; H = out + 98304;
  }
  const int nn = local >> 7, k = local & 127;
  const float v = W[k * nout + nn];
  const unsigned hb = rne_bf16(v);
  const float hf = __uint_as_float(hb << 16);
  const unsigned lb = rne_bf16(v - hf);
  H[local] = (short)hb;
  H[local + nout * 128] = (short)lb;
}

// ---------------- GEMM A (fp32 X): Yh/Yl = split(relu(X@W+b)) ---------------
__global__ __launch_bounds__(256, 2) void gemm_in_kernel(
    const float* __restrict__ X, const short* __restrict__ WtH,
    const short* __restrict__ WtL, const float* __restrict__ bias,
    short* __restrict__ Yh, short* __restrict__ Yl, int nrows, int ntiles) {
  constexpr int NOUT = 128;
  constexpr int NT = NOUT / 16;
  constexpr int LDB = 128 * 2 + 16;
  constexpr int PLANE = NOUT * LDB;
  __shared__ char lds[2 * PLANE];

  const int tid = threadIdx.x;
  for (int u = tid; u < 2 * NOUT * 16; u += 256) {
    const int plane = u / (NOUT * 16);
    const int v = u % (NOUT * 16);
    const int nrow = v >> 4, seg = v & 15;
    const short* src = plane ? WtL : WtH;
    const float4 d = *(const float4*)&src[nrow * 128 + seg * 8];
    *(float4*)&lds[plane * PLANE + nrow * LDB + seg * 16] = d;
  }
  __syncthreads();

  const int lane = tid & 63;
  const int wv = tid >> 6;
  const int li = lane & 15;
  const int kg = lane >> 4;

  float bv[NT];
#pragma unroll
  for (int t = 0; t < NT; ++t) bv[t] = bias[t * 16 + li];

  for (int tile = blockIdx.x; tile < ntiles; tile += gridDim.x) {
    const int row = tile * 64 + wv * 16 + li;
    const int rowc = (row < nrows) ? row : (nrows - 1);
    const float* xrow = X + (size_t)rowc * 128;

    f32x4 acc[NT];
#pragma unroll
    for (int t = 0; t < NT; ++t) acc[t] = (f32x4){0.f, 0.f, 0.f, 0.f};

#pragma unroll
    for (int c = 0; c < 4; ++c) {
      const float4 p0 = *(const float4*)&xrow[c * 32 + kg * 8];
      const float4 p1 = *(const float4*)&xrow[c * 32 + kg * 8 + 4];
      float f[8] = {p0.x, p0.y, p0.z, p0.w, p1.x, p1.y, p1.z, p1.w};
      bf16x8 ah, al;
#pragma unroll
      for (int e = 0; e < 8; ++e) {
        const unsigned hb = rne_bf16(f[e]);
        const float hf = __uint_as_float(hb << 16);
        ah[e] = (short)hb;
        al[e] = (short)rne_bf16(f[e] - hf);
      }
      const int kb = c * 64 + kg * 16;
#pragma unroll
      for (int t = 0; t < NT; ++t) {
        const int boff = (t * 16 + li) * LDB + kb;
        const bf16x8 bh = *(const bf16x8*)&lds[boff];
        const bf16x8 bl = *(const bf16x8*)&lds[PLANE + boff];
        acc[t] = __builtin_amdgcn_mfma_f32_16x16x32_bf16(al, bh, acc[t], 0, 0, 0);
        acc[t] = __builtin_amdgcn_mfma_f32_16x16x32_bf16(ah, bl, acc[t], 0, 0, 0);
        acc[t] = __builtin_amdgcn_mfma_f32_16x16x32_bf16(ah, bh, acc[t], 0, 0, 0);
      }
    }

    const int orow = tile * 64 + wv * 16 + kg * 4;
#pragma unroll
    for (int t = 0; t < NT; ++t) {
      const int col = t * 16 + li;
#pragma unroll
      for (int r = 0; r < 4; ++r) {
        const int rr = orow + r;
        if (rr < nrows) {
          const float o = fmaxf(acc[t][r] + bv[t], 0.f);
          const unsigned hb = rne_bf16(o);
          const float hf = __uint_as_float(hb << 16);
          Yh[(size_t)rr * 128 + col] = (short)hb;
          Yl[(size_t)rr * 128 + col] = (short)rne_bf16(o - hf);
        }
      }
    }
  }
}

// ---------------- GEMM B v2 (bf16-plane X): 64 rows/wave ---------------------
template <int NOUT>
__global__ __launch_bounds__(256, 2) void gemm_pl_kernel(
    const short* __restrict__ Xh, const short* __restrict__ Xl,
    const short* __restrict__ WtH, const short* __restrict__ WtL,
    const float* __restrict__ bias, float* __restrict__ Y, int nrows,
    int ntiles) {
  constexpr int NT = NOUT / 16;
  constexpr int LDB = 128 * 2 + 16;
  constexpr int PLANE = NOUT * LDB;
  __shared__ char lds[2 * PLANE];

  const int tid = threadIdx.x;
  for (int u = tid; u < 2 * NOUT * 16; u += 256) {
    const int plane = u / (NOUT * 16);
    const int v = u % (NOUT * 16);
    const int nrow = v >> 4, seg = v & 15;
    const short* src = plane ? WtL : WtH;
    const float4 d = *(const float4*)&src[nrow * 128 + seg * 8];
    *(float4*)&lds[plane * PLANE + nrow * LDB + seg * 16] = d;
  }
  __syncthreads();

  const int lane = tid & 63;
  const int wv = tid >> 6;
  const int li = lane & 15;
  const int kg = lane >> 4;

  float bv[NT];
#pragma unroll
  for (int t = 0; t < NT; ++t) bv[t] = bias[t * 16 + li];

  for (int tile = blockIdx.x; tile < ntiles; tile += gridDim.x) {
    const int rowbase = tile * 256 + wv * 64;

    f32x4 acc[4][NT];
#pragma unroll
    for (int rg = 0; rg < 4; ++rg)
#pragma unroll
      for (int t = 0; t < NT; ++t) acc[rg][t] = (f32x4){0.f, 0.f, 0.f, 0.f};

#pragma unroll
    for (int c = 0; c < 4; ++c) {
      bf16x8 ah[4], al[4];
#pragma unroll
      for (int rg = 0; rg < 4; ++rg) {
        const int row = rowbase + rg * 16 + li;
        const int rowc = (row < nrows) ? row : (nrows - 1);
        ah[rg] = *(const bf16x8*)&Xh[(size_t)rowc * 128 + c * 32 + kg * 8];
        al[rg] = *(const bf16x8*)&Xl[(size_t)rowc * 128 + c * 32 + kg * 8];
      }
      const int kb = c * 64 + kg * 16;
#pragma unroll
      for (int t = 0; t < NT; ++t) {
        const int boff = (t * 16 + li) * LDB + kb;
        const bf16x8 bh = *(const bf16x8*)&lds[boff];
        const bf16x8 bl = *(const bf16x8*)&lds[PLANE + boff];
#pragma unroll
        for (int rg = 0; rg < 4; ++rg) {
          acc[rg][t] =
              __builtin_amdgcn_mfma_f32_16x16x32_bf16(al[rg], bh, acc[rg][t], 0, 0, 0);
          acc[rg][t] =
              __builtin_amdgcn_mfma_f32_16x16x32_bf16(ah[rg], bl, acc[rg][t], 0, 0, 0);
          acc[rg][t] =
              __builtin_amdgcn_mfma_f32_16x16x32_bf16(ah[rg], bh, acc[rg][t], 0, 0, 0);
        }
      }
    }

#pragma unroll
    for (int rg = 0; rg < 4; ++rg) {
      const int orow = rowbase + rg * 16 + kg * 4;
#pragma unroll
      for (int t = 0; t < NT; ++t) {
        const int col = t * 16 + li;
#pragma unroll
        for (int r = 0; r < 4; ++r) {
          const int rr = orow + r;
          if (rr < nrows) Y[(size_t)rr * NOUT + col] = acc[rg][t][r] + bv[t];
        }
      }
    }
  }
}

// ---------------- MaxK: radix-select top-16 -> (cols u8[16], vals f32[16]) --
__global__ __launch_bounds__(256) void maxk_kernel(
    const float* __restrict__ T, unsigned char* __restrict__ Cs,
    float* __restrict__ Vs, int nrows) {
  const int lane = threadIdx.x & 63;
  const int wid = threadIdx.x >> 6;
  const unsigned long long below = ((unsigned long long)1 << lane) - 1;

  for (int row = blockIdx.x * 4 + wid; row < nrows; row += gridDim.x * 4) {
    const float o0 = T[(size_t)row * 128 + lane];
    const float o1 = T[(size_t)row * 128 + 64 + lane];
    const unsigned u0 = __float_as_uint(o0);
    const unsigned u1 = __float_as_uint(o1);
    const unsigned k0 = u0 ^ (((unsigned)((int)u0 >> 31)) | 0x80000000u);
    const unsigned k1 = u1 ^ (((unsigned)((int)u1 >> 31)) | 0x80000000u);

    unsigned P = 0;
    int kth = 16;
#pragma unroll
    for (int b = 31; b >= 0; --b) {
      const unsigned long long ball0 = __ballot(((k0 ^ P) >> b) == 1u);
      const unsigned long long ball1 = __ballot(((k1 ^ P) >> b) == 1u);
      const int c = __popcll(ball0) + __popcll(ball1);
      if (c >= kth)
        P |= (1u << b);
      else
        kth -= c;
    }
    const bool gt0 = k0 > P, gt1 = k1 > P;
    const unsigned long long g0 = __ballot(gt0);
    const unsigned long long g1 = __ballot(gt1);
    const int need = 16 - __popcll(g0) - __popcll(g1);
    const unsigned long long e0 = __ballot(k0 == P);
    const unsigned long long e1 = __ballot(k1 == P);
    const int need1 = need - __popcll(e0);
    const bool s0 = gt0 || (((e0 >> lane) & 1) &&
                            ((int)__popcll(e0 & below) < need));
    const bool s1 = gt1 || (((e1 >> lane) & 1) &&
                            ((int)__popcll(e1 & below) < need1));
    const unsigned long long m0 = __ballot(s0);
    const unsigned long long m1 = __ballot(s1);

    const int p0 = __popcll(m0 & below);
    const int p1 = __popcll(m0) + __popcll(m1 & below);
    if (s0) {
      Vs[(size_t)row * 16 + p0] = o0;
      Cs[(size_t)row * 16 + p0] = (unsigned char)lane;
    }
    if (s1) {
      Vs[(size_t)row * 16 + p1] = o1;
      Cs[(size_t)row * 16 + p1] = (unsigned char)(lane + 64);
    }
  }
}

// ---------------- CSR build v2: two-level binning ---------------------------
__global__ __launch_bounds__(256) void bhist_kernel(const int* __restrict__ dst,
                                                    int* __restrict__ BC,
                                                    int E) {
  __shared__ int bh[NBUK];
  for (int i = threadIdx.x; i < NBUK; i += 256) bh[i] = 0;
  __syncthreads();
  const int stride = gridDim.x * 256;
  for (int e = blockIdx.x * 256 + threadIdx.x; e < E; e += stride)
    atomicAdd(&bh[dst[e] >> BSHIFT], 1);
  __syncthreads();
  for (int i = threadIdx.x; i < NBUK; i += 256)
    if (bh[i]) atomicAdd(&BC[i], bh[i]);
}

__global__ __launch_bounds__(NBUK) void bscan_kernel(
    const int* __restrict__ BC, int* __restrict__ bases,
    int* __restrict__ bcur, int* __restrict__ rs, int n, int E) {
  __shared__ int sc[NBUK];
  const int t = threadIdx.x;
  const int c = BC[t];
  sc[t] = c;
  __syncthreads();
  for (int st = 1; st < NBUK; st <<= 1) {
    const int v = sc[t];
    const int u = (t >= st) ? sc[t - st] : 0;
    __syncthreads();
    sc[t] = v + u;
    __syncthreads();
  }
  const int excl = sc[t] - c;
  bases[t] = excl;
  bcur[t] = excl;
  if (t == 0) rs[n] = E;
}

__global__ __launch_bounds__(256) void bin_kernel(
    const int* __restrict__ src, const int* __restrict__ dst,
    int* __restrict__ bcur, uint2* __restrict__ binned, int E, int chunk) {
  __shared__ int cnt[NBUK], off[NBUK], gbase[NBUK];
  __shared__ unsigned short bktof[4096];
  __shared__ uint2 buf[4096];
  const int t = threadIdx.x;
  const int beg = blockIdx.x * chunk;
  const int m = min(chunk, E - beg);
  if (m <= 0) return;

  for (int i = t; i < NBUK; i += 256) cnt[i] = 0;
  __syncthreads();

  int d[16], s[16], lp[16], bk[16];
#pragma unroll
  for (int i = 0; i < 16; ++i) {
    const int j = i * 256 + t;
    if (j < m) {
      d[i] = dst[beg + j];
      s[i] = src[beg + j];
      bk[i] = d[i] >> BSHIFT;
      lp[i] = atomicAdd(&cnt[bk[i]], 1);
    } else {
      bk[i] = -1;
    }
  }
  __syncthreads();

  for (int i = t; i < NBUK; i += 256) off[i] = cnt[i];
  __syncthreads();
  for (int st = 1; st < NBUK; st <<= 1) {
    int v0, v1, u0, u1;
    {
      const int i0 = t, i1 = t + 256;
      v0 = off[i0]; u0 = (i0 >= st) ? off[i0 - st] : 0;
      v1 = off[i1]; u1 = (i1 >= st) ? off[i1 - st] : 0;
    }
    __syncthreads();
    off[t] = v0 + u0;
    off[t + 256] = v1 + u1;
    __syncthreads();
  }

  for (int i = t; i < NBUK; i += 256) {
    const int c = cnt[i];
    if (c > 0) {
      gbase[i] = atomicAdd(&bcur[i], c);
      const int e0 = off[i] - c;
      for (int k = 0; k < c; ++k) bktof[e0 + k] = (unsigned short)i;
    }
  }
  __syncthreads();

#pragma unroll
  for (int i = 0; i < 16; ++i) {
    if (bk[i] >= 0) {
      buf[(off[bk[i]] - cnt[bk[i]]) + lp[i]] =
          make_uint2((unsigned)d[i], (unsigned)s[i]);
    }
  }
  __syncthreads();

  for (int j = t; j < m; j += 256) {
    const int b = bktof[j];
    const int e0 = off[b] - cnt[b];
    binned[gbase[b] + (j - e0)] = buf[j];
  }
}

__global__ __launch_bounds__(256) void bbuild_kernel(
    const int* __restrict__ bases, const int* __restrict__ BC,
    const uint2* __restrict__ binned, int* __restrict__ rs,
    int* __restrict__ csr_src, int n) {
  __shared__ int nd[256], sc[256], cur[256];
  const int b = blockIdx.x;
  const int t = threadIdx.x;
  const int base = bases[b];
  const int count = BC[b];
  const int node0 = b << BSHIFT;

  nd[t] = 0;
  __syncthreads();
  for (int i = t; i < count; i += 256)
    atomicAdd(&nd[binned[base + i].x & 255], 1);
  __syncthreads();

  sc[t] = nd[t];
  __syncthreads();
  for (int st = 1; st < 256; st <<= 1) {
    const int v = sc[t];
    const int u = (t >= st) ? sc[t - st] : 0;
    __syncthreads();
    sc[t] = v + u;
    __syncthreads();
  }
  const int excl = sc[t] - nd[t];
  cur[t] = excl;
  if (node0 + t < n) rs[node0 + t] = base + excl;
  __syncthreads();

  for (int i = t; i < count; i += 256) {
    const uint2 p = binned[base + i];
    const int pos = atomicAdd(&cur[p.x & 255], 1);
    csr_src[base + pos] = (int)p.y;
  }
}

// ---------------- Gather v6: LDS private-copy scatter -----------------------
// wave per dst row; 16 lanes per edge scatter (col,val) into group-private
// LDS accumulator copy; no atomics; DS in-order gives RMW correctness.
__global__ __launch_bounds__(256) void gather6_kernel(
    const int* __restrict__ rs, const int* __restrict__ csr_src,
    const unsigned char* __restrict__ Cs, const float* __restrict__ Vs,
    const float* __restrict__ eps_p, short* __restrict__ Ah,
    short* __restrict__ Al, int nrows) {
  __shared__ __align__(16) float sv[4][16][16];          // staged vals
  __shared__ __align__(16) unsigned char scb[4][16][16]; // staged cols
  __shared__ float accb[4][4 * 132];                     // 4 copies/wave
  const int lane = threadIdx.x & 63;
  const int wid = threadIdx.x >> 6;
  const float e1 = 1.0f + *eps_p;
  const int ee = lane >> 2;   // staging: edge slot
  const int q = lane & 3;     // staging: quarter
  const int g = lane >> 4;    // scatter: edge group 0..3
  const int p = lane & 15;    // scatter: nnz index
  float* acc = accb[wid];
  float4* acc4 = (float4*)acc;

  for (int r = blockIdx.x * 4 + wid; r < nrows; r += gridDim.x * 4) {
    // zero the 4 private copies (528 floats = 132 float4)
    for (int i = lane; i < 132; i += 64)
      acc4[i] = make_float4(0.f, 0.f, 0.f, 0.f);

    const int beg = rs[r], end = rs[r + 1];
    for (int base = beg; base < end; base += 16) {
      const int cnt = min(16, end - base);
      if (ee < cnt) {
        const int s = csr_src[base + ee];
        if (q == 0) {
          const int4 c4 = *(const int4*)&Cs[(size_t)s * 16];
          *(int4*)&scb[wid][ee][0] = c4;
        }
        const float4 v = *(const float4*)&Vs[(size_t)s * 16 + q * 4];
        *(float4*)&sv[wid][ee][q * 4] = v;
      }
      // scatter: 4 edges concurrent, 16 lanes each, private copy per group
      for (int e = 0; e < cnt; e += 4) {
        const int eg = e + g;
        if (eg < cnt) {
          const int col = scb[wid][eg][p];
          const float val = sv[wid][eg][p];
          acc[g * 132 + col] += val;
        }
      }
    }
    // self term through copy 0 (lanes 0..15 = group 0)
    if (lane < 16) {
      const int c = Cs[(size_t)r * 16 + lane];
      const float v = Vs[(size_t)r * 16 + lane];
      acc[c] += e1 * v;
    }
    // reduce 4 copies; emit bf16 hi/lo planes
    const float a0 = acc[lane] + acc[132 + lane] + acc[264 + lane] +
                     acc[396 + lane];
    const float a1 = acc[64 + lane] + acc[132 + 64 + lane] +
                     acc[264 + 64 + lane] + acc[396 + 64 + lane];
    const unsigned h0 = rne_bf16(a0);
    const unsigned h1 = rne_bf16(a1);
    Ah[(size_t)r * 128 + lane] = (short)h0;
    Ah[(size_t)r * 128 + 64 + lane] = (short)h1;
    Al[(size_t)r * 128 + lane] =
        (short)rne_bf16(a0 - __uint_as_float(h0 << 16));
    Al[(size_t)r * 128 + 64 + lane] =
        (short)rne_bf16(a1 - __uint_as_float(h1 << 16));
  }
}

// ---------------------------------------------------------------------------
extern "C" void kernel_launch(void* const* d_in, const int* in_sizes, int n_in,
                              void* d_out, int out_size, void* d_ws,
                              size_t ws_size, hipStream_t stream) {
  const float* x = (const float*)d_in[0];
  const int* src = (const int*)d_in[1];
  const int* dst = (const int*)d_in[2];
  const float* W_in = (const float*)d_in[3];
  const float* b_in = (const float*)d_in[4];
  const float* W_lin = (const float*)d_in[5];
  const float* b_lin = (const float*)d_in[6];
  const float* eps = (const float*)d_in[7];
  const float* W_out = (const float*)d_in[8];
  const float* b_out = (const float*)d_in[9];
  float* out = (float*)d_out;

  const int n = in_sizes[0] / 128;
  const int E = in_sizes[1];

  char* w = (char*)d_ws;
  float* B = (float*)w;               w += (size_t)n * 128 * 4;
  unsigned char* Cs = (unsigned char*)w; w += (size_t)n * 16;
  float* Vs = (float*)w;              w += (size_t)n * 16 * 4;
  int* rs = (int*)w;                  w += (size_t)(n + 1) * 4;
  int* csr_src = (int*)w;             w += (size_t)E * 4;
  uint2* binned = (uint2*)w;          w += (size_t)E * 8;
  int* BC = (int*)w;                  w += NBUK * 4;
  int* bases = (int*)w;               w += NBUK * 4;
  int* bcur = (int*)w;                w += NBUK * 4;
  short* wtAll = (short*)w;           w += (size_t)114688 * 2;
  short* Ah = (short*)w;              w += (size_t)n * 128 * 2;
  short* Al = (short*)w;              w += (size_t)n * 128 * 2;

  short* wtIn = wtAll;
  short* wtL0 = wtAll + 32768;
  short* wtL1 = wtAll + 65536;
  short* wtOut = wtAll + 98304;

  const int gtiles = (n + 63) / 64;        // gemm_in: 64-row tiles
  const int ptiles = (n + 255) / 256;      // gemm_pl: 256-row tiles
  const int nbuk_eff = (n + 255) >> BSHIFT;
  const int chunk = 4000;
  const int cblocks = (E + chunk - 1) / chunk;
  const dim3 blk(256);

  // ---- CSR build ----
  hipMemsetAsync(BC, 0, NBUK * 4, stream);
  bhist_kernel<<<256, blk, 0, stream>>>(dst, BC, E);
  bscan_kernel<<<1, NBUK, 0, stream>>>(BC, bases, bcur, rs, n, E);
  bin_kernel<<<cblocks, blk, 0, stream>>>(src, dst, bcur, binned, E, chunk);
  bbuild_kernel<<<nbuk_eff, blk, 0, stream>>>(bases, BC, binned, rs, csr_src,
                                              n);

  // ---- weights -> hi/lo bf16 ----
  wt_build_all_kernel<<<(57344 + 255) / 256, blk, 0, stream>>>(W_in, W_lin,
                                                               W_out, wtAll);

  // ---- h = relu(x @ W_in + b_in) -> planes ----
  gemm_in_kernel<<<512, blk, 0, stream>>>(x, wtIn, wtIn + 16384, b_in, Ah, Al,
                                          n, gtiles);

  for (int l = 0; l < 2; ++l) {
    short* wt = l ? wtL1 : wtL0;
    gemm_pl_kernel<128><<<ptiles, blk, 0, stream>>>(
        Ah, Al, wt, wt + 16384, b_lin + (size_t)l * 128, B, n, ptiles);
    maxk_kernel<<<2048, blk, 0, stream>>>(B, Cs, Vs, n);
    gather6_kernel<<<2048, blk, 0, stream>>>(rs, csr_src, Cs, Vs, eps + l, Ah,
                                             Al, n);
  }

  gemm_pl_kernel<64><<<ptiles, blk, 0, stream>>>(Ah, Al, wtOut, wtOut + 8192,
                                                 b_out, out, n, ptiles);
}

// Round 14
// 407.128 us; speedup vs baseline: 2.3257x; 1.0919x over previous
//
#include <hip/hip_runtime.h>
#include <cstdint>
#include <cstddef>

// ---------------------------------------------------------------------------
// MaxKGIN. R14: gemm_in ported to the proven gemm_pl structure (256-row
// tiles, 4 rowgroups/wave -> 4 independent load chains, 12 MFMA per
// W-fragment) — r13's 64-row gemm_in was latency-bound (MfmaUtil 4%, VALU
// 9%, occ 17%, 85us). Aggregation: gather6 LDS private-copy scatter (r13
// winner). CSR: two-level binning. All else frozen from r13 (444us).
// ---------------------------------------------------------------------------

typedef __attribute__((ext_vector_type(8))) short bf16x8;
typedef __attribute__((ext_vector_type(4))) float f32x4;

#define BSHIFT 8
#define NBUK 512  // covers dst>>8 for n <= 131072

__device__ __forceinline__ unsigned rne_bf16(float v) {
  unsigned u = __float_as_uint(v);
  return (u + 0x7fffu + ((u >> 16) & 1u)) >> 16;
}

// ---------------- fused W^T build: all 4 weights -> hi/lo bf16 --------------
__global__ __launch_bounds__(256) void wt_build_all_kernel(
    const float* __restrict__ W_in, const float* __restrict__ W_lin,
    const float* __restrict__ W_out, short* __restrict__ out) {
  const int i = blockIdx.x * 256 + threadIdx.x;
  if (i >= 57344) return;
  const float* W;
  int nout, local;
  short* H;
  if (i < 16384) {
    W = W_in; nout = 128; local = i; H = out;
  } else if (i < 32768) {
    W = W_lin; nout = 128; local = i - 16384; H = out + 32768;
  } else if (i < 49152) {
    W = W_lin + 16384; nout = 128; local = i - 32768; H = out + 65536;
  } else {
    W = W_out; nout = 64; local = i - 49152; H = out + 98304;
  }
  const int nn = local >> 7, k = local & 127;
  const float v = W[k * nout + nn];
  const unsigned hb = rne_bf16(v);
  const float hf = __uint_as_float(hb << 16);
  const unsigned lb = rne_bf16(v - hf);
  H[local] = (short)hb;
  H[local + nout * 128] = (short)lb;
}

// ---------------- GEMM A v2 (fp32 X): 256-row tiles, 4 rowgroups/wave -------
__global__ __launch_bounds__(256, 2) void gemm_in_kernel(
    const float* __restrict__ X, const short* __restrict__ WtH,
    const short* __restrict__ WtL, const float* __restrict__ bias,
    short* __restrict__ Yh, short* __restrict__ Yl, int nrows, int ntiles) {
  constexpr int NOUT = 128;
  constexpr int NT = NOUT / 16;
  constexpr int LDB = 128 * 2 + 16;
  constexpr int PLANE = NOUT * LDB;
  __shared__ char lds[2 * PLANE];

  const int tid = threadIdx.x;
  for (int u = tid; u < 2 * NOUT * 16; u += 256) {
    const int plane = u / (NOUT * 16);
    const int v = u % (NOUT * 16);
    const int nrow = v >> 4, seg = v & 15;
    const short* src = plane ? WtL : WtH;
    const float4 d = *(const float4*)&src[nrow * 128 + seg * 8];
    *(float4*)&lds[plane * PLANE + nrow * LDB + seg * 16] = d;
  }
  __syncthreads();

  const int lane = tid & 63;
  const int wv = tid >> 6;
  const int li = lane & 15;
  const int kg = lane >> 4;

  float bv[NT];
#pragma unroll
  for (int t = 0; t < NT; ++t) bv[t] = bias[t * 16 + li];

  for (int tile = blockIdx.x; tile < ntiles; tile += gridDim.x) {
    const int rowbase = tile * 256 + wv * 64;

    f32x4 acc[4][NT];
#pragma unroll
    for (int rg = 0; rg < 4; ++rg)
#pragma unroll
      for (int t = 0; t < NT; ++t) acc[rg][t] = (f32x4){0.f, 0.f, 0.f, 0.f};

#pragma unroll
    for (int c = 0; c < 4; ++c) {
      bf16x8 ah[4], al[4];
#pragma unroll
      for (int rg = 0; rg < 4; ++rg) {
        const int row = rowbase + rg * 16 + li;
        const int rowc = (row < nrows) ? row : (nrows - 1);
        const float* xrow = X + (size_t)rowc * 128 + c * 32 + kg * 8;
        const float4 p0 = *(const float4*)&xrow[0];
        const float4 p1 = *(const float4*)&xrow[4];
        const float f[8] = {p0.x, p0.y, p0.z, p0.w, p1.x, p1.y, p1.z, p1.w};
#pragma unroll
        for (int e = 0; e < 8; ++e) {
          const unsigned hb = rne_bf16(f[e]);
          const float hf = __uint_as_float(hb << 16);
          ah[rg][e] = (short)hb;
          al[rg][e] = (short)rne_bf16(f[e] - hf);
        }
      }
      const int kb = c * 64 + kg * 16;
#pragma unroll
      for (int t = 0; t < NT; ++t) {
        const int boff = (t * 16 + li) * LDB + kb;
        const bf16x8 bh = *(const bf16x8*)&lds[boff];
        const bf16x8 bl = *(const bf16x8*)&lds[PLANE + boff];
#pragma unroll
        for (int rg = 0; rg < 4; ++rg) {
          acc[rg][t] =
              __builtin_amdgcn_mfma_f32_16x16x32_bf16(al[rg], bh, acc[rg][t], 0, 0, 0);
          acc[rg][t] =
              __builtin_amdgcn_mfma_f32_16x16x32_bf16(ah[rg], bl, acc[rg][t], 0, 0, 0);
          acc[rg][t] =
              __builtin_amdgcn_mfma_f32_16x16x32_bf16(ah[rg], bh, acc[rg][t], 0, 0, 0);
        }
      }
    }

#pragma unroll
    for (int rg = 0; rg < 4; ++rg) {
      const int orow = rowbase + rg * 16 + kg * 4;
#pragma unroll
      for (int t = 0; t < NT; ++t) {
        const int col = t * 16 + li;
#pragma unroll
        for (int r = 0; r < 4; ++r) {
          const int rr = orow + r;
          if (rr < nrows) {
            const float o = fmaxf(acc[rg][t][r] + bv[t], 0.f);
            const unsigned hb = rne_bf16(o);
            const float hf = __uint_as_float(hb << 16);
            Yh[(size_t)rr * 128 + col] = (short)hb;
            Yl[(size_t)rr * 128 + col] = (short)rne_bf16(o - hf);
          }
        }
      }
    }
  }
}

// ---------------- GEMM B v2 (bf16-plane X): 64 rows/wave ---------------------
template <int NOUT>
__global__ __launch_bounds__(256, 2) void gemm_pl_kernel(
    const short* __restrict__ Xh, const short* __restrict__ Xl,
    const short* __restrict__ WtH, const short* __restrict__ WtL,
    const float* __restrict__ bias, float* __restrict__ Y, int nrows,
    int ntiles) {
  constexpr int NT = NOUT / 16;
  constexpr int LDB = 128 * 2 + 16;
  constexpr int PLANE = NOUT * LDB;
  __shared__ char lds[2 * PLANE];

  const int tid = threadIdx.x;
  for (int u = tid; u < 2 * NOUT * 16; u += 256) {
    const int plane = u / (NOUT * 16);
    const int v = u % (NOUT * 16);
    const int nrow = v >> 4, seg = v & 15;
    const short* src = plane ? WtL : WtH;
    const float4 d = *(const float4*)&src[nrow * 128 + seg * 8];
    *(float4*)&lds[plane * PLANE + nrow * LDB + seg * 16] = d;
  }
  __syncthreads();

  const int lane = tid & 63;
  const int wv = tid >> 6;
  const int li = lane & 15;
  const int kg = lane >> 4;

  float bv[NT];
#pragma unroll
  for (int t = 0; t < NT; ++t) bv[t] = bias[t * 16 + li];

  for (int tile = blockIdx.x; tile < ntiles; tile += gridDim.x) {
    const int rowbase = tile * 256 + wv * 64;

    f32x4 acc[4][NT];
#pragma unroll
    for (int rg = 0; rg < 4; ++rg)
#pragma unroll
      for (int t = 0; t < NT; ++t) acc[rg][t] = (f32x4){0.f, 0.f, 0.f, 0.f};

#pragma unroll
    for (int c = 0; c < 4; ++c) {
      bf16x8 ah[4], al[4];
#pragma unroll
      for (int rg = 0; rg < 4; ++rg) {
        const int row = rowbase + rg * 16 + li;
        const int rowc = (row < nrows) ? row : (nrows - 1);
        ah[rg] = *(const bf16x8*)&Xh[(size_t)rowc * 128 + c * 32 + kg * 8];
        al[rg] = *(const bf16x8*)&Xl[(size_t)rowc * 128 + c * 32 + kg * 8];
      }
      const int kb = c * 64 + kg * 16;
#pragma unroll
      for (int t = 0; t < NT; ++t) {
        const int boff = (t * 16 + li) * LDB + kb;
        const bf16x8 bh = *(const bf16x8*)&lds[boff];
        const bf16x8 bl = *(const bf16x8*)&lds[PLANE + boff];
#pragma unroll
        for (int rg = 0; rg < 4; ++rg) {
          acc[rg][t] =
              __builtin_amdgcn_mfma_f32_16x16x32_bf16(al[rg], bh, acc[rg][t], 0, 0, 0);
          acc[rg][t] =
              __builtin_amdgcn_mfma_f32_16x16x32_bf16(ah[rg], bl, acc[rg][t], 0, 0, 0);
          acc[rg][t] =
              __builtin_amdgcn_mfma_f32_16x16x32_bf16(ah[rg], bh, acc[rg][t], 0, 0, 0);
        }
      }
    }

#pragma unroll
    for (int rg = 0; rg < 4; ++rg) {
      const int orow = rowbase + rg * 16 + kg * 4;
#pragma unroll
      for (int t = 0; t < NT; ++t) {
        const int col = t * 16 + li;
#pragma unroll
        for (int r = 0; r < 4; ++r) {
          const int rr = orow + r;
          if (rr < nrows) Y[(size_t)rr * NOUT + col] = acc[rg][t][r] + bv[t];
        }
      }
    }
  }
}

// ---------------- MaxK: radix-select top-16 -> (cols u8[16], vals f32[16]) --
__global__ __launch_bounds__(256) void maxk_kernel(
    const float* __restrict__ T, unsigned char* __restrict__ Cs,
    float* __restrict__ Vs, int nrows) {
  const int lane = threadIdx.x & 63;
  const int wid = threadIdx.x >> 6;
  const unsigned long long below = ((unsigned long long)1 << lane) - 1;

  for (int row = blockIdx.x * 4 + wid; row < nrows; row += gridDim.x * 4) {
    const float o0 = T[(size_t)row * 128 + lane];
    const float o1 = T[(size_t)row * 128 + 64 + lane];
    const unsigned u0 = __float_as_uint(o0);
    const unsigned u1 = __float_as_uint(o1);
    const unsigned k0 = u0 ^ (((unsigned)((int)u0 >> 31)) | 0x80000000u);
    const unsigned k1 = u1 ^ (((unsigned)((int)u1 >> 31)) | 0x80000000u);

    unsigned P = 0;
    int kth = 16;
#pragma unroll
    for (int b = 31; b >= 0; --b) {
      const unsigned long long ball0 = __ballot(((k0 ^ P) >> b) == 1u);
      const unsigned long long ball1 = __ballot(((k1 ^ P) >> b) == 1u);
      const int c = __popcll(ball0) + __popcll(ball1);
      if (c >= kth)
        P |= (1u << b);
      else
        kth -= c;
    }
    const bool gt0 = k0 > P, gt1 = k1 > P;
    const unsigned long long g0 = __ballot(gt0);
    const unsigned long long g1 = __ballot(gt1);
    const int need = 16 - __popcll(g0) - __popcll(g1);
    const unsigned long long e0 = __ballot(k0 == P);
    const unsigned long long e1 = __ballot(k1 == P);
    const int need1 = need - __popcll(e0);
    const bool s0 = gt0 || (((e0 >> lane) & 1) &&
                            ((int)__popcll(e0 & below) < need));
    const bool s1 = gt1 || (((e1 >> lane) & 1) &&
                            ((int)__popcll(e1 & below) < need1));
    const unsigned long long m0 = __ballot(s0);
    const unsigned long long m1 = __ballot(s1);

    const int p0 = __popcll(m0 & below);
    const int p1 = __popcll(m0) + __popcll(m1 & below);
    if (s0) {
      Vs[(size_t)row * 16 + p0] = o0;
      Cs[(size_t)row * 16 + p0] = (unsigned char)lane;
    }
    if (s1) {
      Vs[(size_t)row * 16 + p1] = o1;
      Cs[(size_t)row * 16 + p1] = (unsigned char)(lane + 64);
    }
  }
}

// ---------------- CSR build v2: two-level binning ---------------------------
__global__ __launch_bounds__(256) void bhist_kernel(const int* __restrict__ dst,
                                                    int* __restrict__ BC,
                                                    int E) {
  __shared__ int bh[NBUK];
  for (int i = threadIdx.x; i < NBUK; i += 256) bh[i] = 0;
  __syncthreads();
  const int stride = gridDim.x * 256;
  for (int e = blockIdx.x * 256 + threadIdx.x; e < E; e += stride)
    atomicAdd(&bh[dst[e] >> BSHIFT], 1);
  __syncthreads();
  for (int i = threadIdx.x; i < NBUK; i += 256)
    if (bh[i]) atomicAdd(&BC[i], bh[i]);
}

__global__ __launch_bounds__(NBUK) void bscan_kernel(
    const int* __restrict__ BC, int* __restrict__ bases,
    int* __restrict__ bcur, int* __restrict__ rs, int n, int E) {
  __shared__ int sc[NBUK];
  const int t = threadIdx.x;
  const int c = BC[t];
  sc[t] = c;
  __syncthreads();
  for (int st = 1; st < NBUK; st <<= 1) {
    const int v = sc[t];
    const int u = (t >= st) ? sc[t - st] : 0;
    __syncthreads();
    sc[t] = v + u;
    __syncthreads();
  }
  const int excl = sc[t] - c;
  bases[t] = excl;
  bcur[t] = excl;
  if (t == 0) rs[n] = E;
}

__global__ __launch_bounds__(256) void bin_kernel(
    const int* __restrict__ src, const int* __restrict__ dst,
    int* __restrict__ bcur, uint2* __restrict__ binned, int E, int chunk) {
  __shared__ int cnt[NBUK], off[NBUK], gbase[NBUK];
  __shared__ unsigned short bktof[4096];
  __shared__ uint2 buf[4096];
  const int t = threadIdx.x;
  const int beg = blockIdx.x * chunk;
  const int m = min(chunk, E - beg);
  if (m <= 0) return;

  for (int i = t; i < NBUK; i += 256) cnt[i] = 0;
  __syncthreads();

  int d[16], s[16], lp[16], bk[16];
#pragma unroll
  for (int i = 0; i < 16; ++i) {
    const int j = i * 256 + t;
    if (j < m) {
      d[i] = dst[beg + j];
      s[i] = src[beg + j];
      bk[i] = d[i] >> BSHIFT;
      lp[i] = atomicAdd(&cnt[bk[i]], 1);
    } else {
      bk[i] = -1;
    }
  }
  __syncthreads();

  for (int i = t; i < NBUK; i += 256) off[i] = cnt[i];
  __syncthreads();
  for (int st = 1; st < NBUK; st <<= 1) {
    int v0, v1, u0, u1;
    {
      const int i0 = t, i1 = t + 256;
      v0 = off[i0]; u0 = (i0 >= st) ? off[i0 - st] : 0;
      v1 = off[i1]; u1 = (i1 >= st) ? off[i1 - st] : 0;
    }
    __syncthreads();
    off[t] = v0 + u0;
    off[t + 256] = v1 + u1;
    __syncthreads();
  }

  for (int i = t; i < NBUK; i += 256) {
    const int c = cnt[i];
    if (c > 0) {
      gbase[i] = atomicAdd(&bcur[i], c);
      const int e0 = off[i] - c;
      for (int k = 0; k < c; ++k) bktof[e0 + k] = (unsigned short)i;
    }
  }
  __syncthreads();

#pragma unroll
  for (int i = 0; i < 16; ++i) {
    if (bk[i] >= 0) {
      buf[(off[bk[i]] - cnt[bk[i]]) + lp[i]] =
          make_uint2((unsigned)d[i], (unsigned)s[i]);
    }
  }
  __syncthreads();

  for (int j = t; j < m; j += 256) {
    const int b = bktof[j];
    const int e0 = off[b] - cnt[b];
    binned[gbase[b] + (j - e0)] = buf[j];
  }
}

__global__ __launch_bounds__(256) void bbuild_kernel(
    const int* __restrict__ bases, const int* __restrict__ BC,
    const uint2* __restrict__ binned, int* __restrict__ rs,
    int* __restrict__ csr_src, int n) {
  __shared__ int nd[256], sc[256], cur[256];
  const int b = blockIdx.x;
  const int t = threadIdx.x;
  const int base = bases[b];
  const int count = BC[b];
  const int node0 = b << BSHIFT;

  nd[t] = 0;
  __syncthreads();
  for (int i = t; i < count; i += 256)
    atomicAdd(&nd[binned[base + i].x & 255], 1);
  __syncthreads();

  sc[t] = nd[t];
  __syncthreads();
  for (int st = 1; st < 256; st <<= 1) {
    const int v = sc[t];
    const int u = (t >= st) ? sc[t - st] : 0;
    __syncthreads();
    sc[t] = v + u;
    __syncthreads();
  }
  const int excl = sc[t] - nd[t];
  cur[t] = excl;
  if (node0 + t < n) rs[node0 + t] = base + excl;
  __syncthreads();

  for (int i = t; i < count; i += 256) {
    const uint2 p = binned[base + i];
    const int pos = atomicAdd(&cur[p.x & 255], 1);
    csr_src[base + pos] = (int)p.y;
  }
}

// ---------------- Gather v6: LDS private-copy scatter -----------------------
__global__ __launch_bounds__(256) void gather6_kernel(
    const int* __restrict__ rs, const int* __restrict__ csr_src,
    const unsigned char* __restrict__ Cs, const float* __restrict__ Vs,
    const float* __restrict__ eps_p, short* __restrict__ Ah,
    short* __restrict__ Al, int nrows) {
  __shared__ __align__(16) float sv[4][16][16];          // staged vals
  __shared__ __align__(16) unsigned char scb[4][16][16]; // staged cols
  __shared__ float accb[4][4 * 132];                     // 4 copies/wave
  const int lane = threadIdx.x & 63;
  const int wid = threadIdx.x >> 6;
  const float e1 = 1.0f + *eps_p;
  const int ee = lane >> 2;   // staging: edge slot
  const int q = lane & 3;     // staging: quarter
  const int g = lane >> 4;    // scatter: edge group 0..3
  const int p = lane & 15;    // scatter: nnz index
  float* acc = accb[wid];
  float4* acc4 = (float4*)acc;

  for (int r = blockIdx.x * 4 + wid; r < nrows; r += gridDim.x * 4) {
    for (int i = lane; i < 132; i += 64)
      acc4[i] = make_float4(0.f, 0.f, 0.f, 0.f);

    const int beg = rs[r], end = rs[r + 1];
    for (int base = beg; base < end; base += 16) {
      const int cnt = min(16, end - base);
      if (ee < cnt) {
        const int s = csr_src[base + ee];
        if (q == 0) {
          const int4 c4 = *(const int4*)&Cs[(size_t)s * 16];
          *(int4*)&scb[wid][ee][0] = c4;
        }
        const float4 v = *(const float4*)&Vs[(size_t)s * 16 + q * 4];
        *(float4*)&sv[wid][ee][q * 4] = v;
      }
      for (int e = 0; e < cnt; e += 4) {
        const int eg = e + g;
        if (eg < cnt) {
          const int col = scb[wid][eg][p];
          const float val = sv[wid][eg][p];
          acc[g * 132 + col] += val;
        }
      }
    }
    if (lane < 16) {
      const int c = Cs[(size_t)r * 16 + lane];
      const float v = Vs[(size_t)r * 16 + lane];
      acc[c] += e1 * v;
    }
    const float a0 = acc[lane] + acc[132 + lane] + acc[264 + lane] +
                     acc[396 + lane];
    const float a1 = acc[64 + lane] + acc[132 + 64 + lane] +
                     acc[264 + 64 + lane] + acc[396 + 64 + lane];
    const unsigned h0 = rne_bf16(a0);
    const unsigned h1 = rne_bf16(a1);
    Ah[(size_t)r * 128 + lane] = (short)h0;
    Ah[(size_t)r * 128 + 64 + lane] = (short)h1;
    Al[(size_t)r * 128 + lane] =
        (short)rne_bf16(a0 - __uint_as_float(h0 << 16));
    Al[(size_t)r * 128 + 64 + lane] =
        (short)rne_bf16(a1 - __uint_as_float(h1 << 16));
  }
}

// ---------------------------------------------------------------------------
extern "C" void kernel_launch(void* const* d_in, const int* in_sizes, int n_in,
                              void* d_out, int out_size, void* d_ws,
                              size_t ws_size, hipStream_t stream) {
  const float* x = (const float*)d_in[0];
  const int* src = (const int*)d_in[1];
  const int* dst = (const int*)d_in[2];
  const float* W_in = (const float*)d_in[3];
  const float* b_in = (const float*)d_in[4];
  const float* W_lin = (const float*)d_in[5];
  const float* b_lin = (const float*)d_in[6];
  const float* eps = (const float*)d_in[7];
  const float* W_out = (const float*)d_in[8];
  const float* b_out = (const float*)d_in[9];
  float* out = (float*)d_out;

  const int n = in_sizes[0] / 128;
  const int E = in_sizes[1];

  char* w = (char*)d_ws;
  float* B = (float*)w;               w += (size_t)n * 128 * 4;
  unsigned char* Cs = (unsigned char*)w; w += (size_t)n * 16;
  float* Vs = (float*)w;              w += (size_t)n * 16 * 4;
  int* rs = (int*)w;                  w += (size_t)(n + 1) * 4;
  int* csr_src = (int*)w;             w += (size_t)E * 4;
  uint2* binned = (uint2*)w;          w += (size_t)E * 8;
  int* BC = (int*)w;                  w += NBUK * 4;
  int* bases = (int*)w;               w += NBUK * 4;
  int* bcur = (int*)w;                w += NBUK * 4;
  short* wtAll = (short*)w;           w += (size_t)114688 * 2;
  short* Ah = (short*)w;              w += (size_t)n * 128 * 2;
  short* Al = (short*)w;              w += (size_t)n * 128 * 2;

  short* wtIn = wtAll;
  short* wtL0 = wtAll + 32768;
  short* wtL1 = wtAll + 65536;
  short* wtOut = wtAll + 98304;

  const int ptiles = (n + 255) / 256;      // 256-row tiles (all GEMMs)
  const int nbuk_eff = (n + 255) >> BSHIFT;
  const int chunk = 4000;
  const int cblocks = (E + chunk - 1) / chunk;
  const dim3 blk(256);

  // ---- CSR build ----
  hipMemsetAsync(BC, 0, NBUK * 4, stream);
  bhist_kernel<<<256, blk, 0, stream>>>(dst, BC, E);
  bscan_kernel<<<1, NBUK, 0, stream>>>(BC, bases, bcur, rs, n, E);
  bin_kernel<<<cblocks, blk, 0, stream>>>(src, dst, bcur, binned, E, chunk);
  bbuild_kernel<<<nbuk_eff, blk, 0, stream>>>(bases, BC, binned, rs, csr_src,
                                              n);

  // ---- weights -> hi/lo bf16 ----
  wt_build_all_kernel<<<(57344 + 255) / 256, blk, 0, stream>>>(W_in, W_lin,
                                                               W_out, wtAll);

  // ---- h = relu(x @ W_in + b_in) -> planes ----
  gemm_in_kernel<<<ptiles, blk, 0, stream>>>(x, wtIn, wtIn + 16384, b_in, Ah,
                                             Al, n, ptiles);

  for (int l = 0; l < 2; ++l) {
    short* wt = l ? wtL1 : wtL0;
    gemm_pl_kernel<128><<<ptiles, blk, 0, stream>>>(
        Ah, Al, wt, wt + 16384, b_lin + (size_t)l * 128, B, n, ptiles);
    maxk_kernel<<<2048, blk, 0, stream>>>(B, Cs, Vs, n);
    gather6_kernel<<<2048, blk, 0, stream>>>(rs, csr_src, Cs, Vs, eps + l, Ah,
                                             Al, n);
  }

  gemm_pl_kernel<64><<<ptiles, blk, 0, stream>>>(Ah, Al, wtOut, wtOut + 8192,
                                                 b_out, out, n, ptiles);
}

// Round 15
// 393.820 us; speedup vs baseline: 2.4043x; 1.0338x over previous
//
#include <hip/hip_runtime.h>
#include <cstdint>
#include <cstddef>

// ---------------------------------------------------------------------------
// MaxKGIN. R15: maxk v3 — 4 rows/wave via 16-lane subgroups (shared ballots,
// per-lane slice popc, 4 independent radix chains for ILP) + early exit when
// candidate set == remaining k (threshold P, select k>=P). r14's maxk was a
// single serial ballot->SALU chain per wave (61us, VALU 48%).
// GEMMs: 256-row tiles, 4 rowgroups/wave. gather6: LDS private-copy scatter.
// CSR: two-level binning. All else frozen from r14 (407us).
// ---------------------------------------------------------------------------

typedef __attribute__((ext_vector_type(8))) short bf16x8;
typedef __attribute__((ext_vector_type(4))) float f32x4;

#define BSHIFT 8
#define NBUK 512  // covers dst>>8 for n <= 131072

__device__ __forceinline__ unsigned rne_bf16(float v) {
  unsigned u = __float_as_uint(v);
  return (u + 0x7fffu + ((u >> 16) & 1u)) >> 16;
}

// ---------------- fused W^T build: all 4 weights -> hi/lo bf16 --------------
__global__ __launch_bounds__(256) void wt_build_all_kernel(
    const float* __restrict__ W_in, const float* __restrict__ W_lin,
    const float* __restrict__ W_out, short* __restrict__ out) {
  const int i = blockIdx.x * 256 + threadIdx.x;
  if (i >= 57344) return;
  const float* W;
  int nout, local;
  short* H;
  if (i < 16384) {
    W = W_in; nout = 128; local = i; H = out;
  } else if (i < 32768) {
    W = W_lin; nout = 128; local = i - 16384; H = out + 32768;
  } else if (i < 49152) {
    W = W_lin + 16384; nout = 128; local = i - 32768; H = out + 65536;
  } else {
    W = W_out; nout = 64; local = i - 49152; H = out + 98304;
  }
  const int nn = local >> 7, k = local & 127;
  const float v = W[k * nout + nn];
  const unsigned hb = rne_bf16(v);
  const float hf = __uint_as_float(hb << 16);
  const unsigned lb = rne_bf16(v - hf);
  H[local] = (short)hb;
  H[local + nout * 128] = (short)lb;
}

// ---------------- GEMM A v2 (fp32 X): 256-row tiles, 4 rowgroups/wave -------
__global__ __launch_bounds__(256, 2) void gemm_in_kernel(
    const float* __restrict__ X, const short* __restrict__ WtH,
    const short* __restrict__ WtL, const float* __restrict__ bias,
    short* __restrict__ Yh, short* __restrict__ Yl, int nrows, int ntiles) {
  constexpr int NOUT = 128;
  constexpr int NT = NOUT / 16;
  constexpr int LDB = 128 * 2 + 16;
  constexpr int PLANE = NOUT * LDB;
  __shared__ char lds[2 * PLANE];

  const int tid = threadIdx.x;
  for (int u = tid; u < 2 * NOUT * 16; u += 256) {
    const int plane = u / (NOUT * 16);
    const int v = u % (NOUT * 16);
    const int nrow = v >> 4, seg = v & 15;
    const short* src = plane ? WtL : WtH;
    const float4 d = *(const float4*)&src[nrow * 128 + seg * 8];
    *(float4*)&lds[plane * PLANE + nrow * LDB + seg * 16] = d;
  }
  __syncthreads();

  const int lane = tid & 63;
  const int wv = tid >> 6;
  const int li = lane & 15;
  const int kg = lane >> 4;

  float bv[NT];
#pragma unroll
  for (int t = 0; t < NT; ++t) bv[t] = bias[t * 16 + li];

  for (int tile = blockIdx.x; tile < ntiles; tile += gridDim.x) {
    const int rowbase = tile * 256 + wv * 64;

    f32x4 acc[4][NT];
#pragma unroll
    for (int rg = 0; rg < 4; ++rg)
#pragma unroll
      for (int t = 0; t < NT; ++t) acc[rg][t] = (f32x4){0.f, 0.f, 0.f, 0.f};

#pragma unroll
    for (int c = 0; c < 4; ++c) {
      bf16x8 ah[4], al[4];
#pragma unroll
      for (int rg = 0; rg < 4; ++rg) {
        const int row = rowbase + rg * 16 + li;
        const int rowc = (row < nrows) ? row : (nrows - 1);
        const float* xrow = X + (size_t)rowc * 128 + c * 32 + kg * 8;
        const float4 p0 = *(const float4*)&xrow[0];
        const float4 p1 = *(const float4*)&xrow[4];
        const float f[8] = {p0.x, p0.y, p0.z, p0.w, p1.x, p1.y, p1.z, p1.w};
#pragma unroll
        for (int e = 0; e < 8; ++e) {
          const unsigned hb = rne_bf16(f[e]);
          const float hf = __uint_as_float(hb << 16);
          ah[rg][e] = (short)hb;
          al[rg][e] = (short)rne_bf16(f[e] - hf);
        }
      }
      const int kb = c * 64 + kg * 16;
#pragma unroll
      for (int t = 0; t < NT; ++t) {
        const int boff = (t * 16 + li) * LDB + kb;
        const bf16x8 bh = *(const bf16x8*)&lds[boff];
        const bf16x8 bl = *(const bf16x8*)&lds[PLANE + boff];
#pragma unroll
        for (int rg = 0; rg < 4; ++rg) {
          acc[rg][t] =
              __builtin_amdgcn_mfma_f32_16x16x32_bf16(al[rg], bh, acc[rg][t], 0, 0, 0);
          acc[rg][t] =
              __builtin_amdgcn_mfma_f32_16x16x32_bf16(ah[rg], bl, acc[rg][t], 0, 0, 0);
          acc[rg][t] =
              __builtin_amdgcn_mfma_f32_16x16x32_bf16(ah[rg], bh, acc[rg][t], 0, 0, 0);
        }
      }
    }

#pragma unroll
    for (int rg = 0; rg < 4; ++rg) {
      const int orow = rowbase + rg * 16 + kg * 4;
#pragma unroll
      for (int t = 0; t < NT; ++t) {
        const int col = t * 16 + li;
#pragma unroll
        for (int r = 0; r < 4; ++r) {
          const int rr = orow + r;
          if (rr < nrows) {
            const float o = fmaxf(acc[rg][t][r] + bv[t], 0.f);
            const unsigned hb = rne_bf16(o);
            const float hf = __uint_as_float(hb << 16);
            Yh[(size_t)rr * 128 + col] = (short)hb;
            Yl[(size_t)rr * 128 + col] = (short)rne_bf16(o - hf);
          }
        }
      }
    }
  }
}

// ---------------- GEMM B v2 (bf16-plane X): 64 rows/wave ---------------------
template <int NOUT>
__global__ __launch_bounds__(256, 2) void gemm_pl_kernel(
    const short* __restrict__ Xh, const short* __restrict__ Xl,
    const short* __restrict__ WtH, const short* __restrict__ WtL,
    const float* __restrict__ bias, float* __restrict__ Y, int nrows,
    int ntiles) {
  constexpr int NT = NOUT / 16;
  constexpr int LDB = 128 * 2 + 16;
  constexpr int PLANE = NOUT * LDB;
  __shared__ char lds[2 * PLANE];

  const int tid = threadIdx.x;
  for (int u = tid; u < 2 * NOUT * 16; u += 256) {
    const int plane = u / (NOUT * 16);
    const int v = u % (NOUT * 16);
    const int nrow = v >> 4, seg = v & 15;
    const short* src = plane ? WtL : WtH;
    const float4 d = *(const float4*)&src[nrow * 128 + seg * 8];
    *(float4*)&lds[plane * PLANE + nrow * LDB + seg * 16] = d;
  }
  __syncthreads();

  const int lane = tid & 63;
  const int wv = tid >> 6;
  const int li = lane & 15;
  const int kg = lane >> 4;

  float bv[NT];
#pragma unroll
  for (int t = 0; t < NT; ++t) bv[t] = bias[t * 16 + li];

  for (int tile = blockIdx.x; tile < ntiles; tile += gridDim.x) {
    const int rowbase = tile * 256 + wv * 64;

    f32x4 acc[4][NT];
#pragma unroll
    for (int rg = 0; rg < 4; ++rg)
#pragma unroll
      for (int t = 0; t < NT; ++t) acc[rg][t] = (f32x4){0.f, 0.f, 0.f, 0.f};

#pragma unroll
    for (int c = 0; c < 4; ++c) {
      bf16x8 ah[4], al[4];
#pragma unroll
      for (int rg = 0; rg < 4; ++rg) {
        const int row = rowbase + rg * 16 + li;
        const int rowc = (row < nrows) ? row : (nrows - 1);
        ah[rg] = *(const bf16x8*)&Xh[(size_t)rowc * 128 + c * 32 + kg * 8];
        al[rg] = *(const bf16x8*)&Xl[(size_t)rowc * 128 + c * 32 + kg * 8];
      }
      const int kb = c * 64 + kg * 16;
#pragma unroll
      for (int t = 0; t < NT; ++t) {
        const int boff = (t * 16 + li) * LDB + kb;
        const bf16x8 bh = *(const bf16x8*)&lds[boff];
        const bf16x8 bl = *(const bf16x8*)&lds[PLANE + boff];
#pragma unroll
        for (int rg = 0; rg < 4; ++rg) {
          acc[rg][t] =
              __builtin_amdgcn_mfma_f32_16x16x32_bf16(al[rg], bh, acc[rg][t], 0, 0, 0);
          acc[rg][t] =
              __builtin_amdgcn_mfma_f32_16x16x32_bf16(ah[rg], bl, acc[rg][t], 0, 0, 0);
          acc[rg][t] =
              __builtin_amdgcn_mfma_f32_16x16x32_bf16(ah[rg], bh, acc[rg][t], 0, 0, 0);
        }
      }
    }

#pragma unroll
    for (int rg = 0; rg < 4; ++rg) {
      const int orow = rowbase + rg * 16 + kg * 4;
#pragma unroll
      for (int t = 0; t < NT; ++t) {
        const int col = t * 16 + li;
#pragma unroll
        for (int r = 0; r < 4; ++r) {
          const int rr = orow + r;
          if (rr < nrows) Y[(size_t)rr * NOUT + col] = acc[rg][t][r] + bv[t];
        }
      }
    }
  }
}

// ---------------- MaxK v3: 4 rows/wave, subgroup radix + early exit ---------
// lane=(sub,s): subgroup sub owns row quad*4+sub; lane s holds 8 values at
// cols j*16+s. One ballot per j serves all 4 subgroups (16-bit slices).
// Early exit when candidate count == remaining k (select key >= P).
__global__ __launch_bounds__(256) void maxk_kernel(
    const float* __restrict__ T, unsigned char* __restrict__ Cs,
    float* __restrict__ Vs, int nrows) {
  const int lane = threadIdx.x & 63;
  const int wid = threadIdx.x >> 6;
  const int sub = lane >> 4;
  const int s = lane & 15;
  const int shift = sub * 16;
  const unsigned below = (1u << s) - 1u;
  const int nquads = (nrows + 3) / 4;

  for (int quad = blockIdx.x * 4 + wid; quad < nquads; quad += gridDim.x * 4) {
    const int row = quad * 4 + sub;
    const int rowc = (row < nrows) ? row : (nrows - 1);
    const float* Trow = T + (size_t)rowc * 128;

    float v[8];
    unsigned k[8];
#pragma unroll
    for (int j = 0; j < 8; ++j) {
      v[j] = Trow[j * 16 + s];
      const unsigned u = __float_as_uint(v[j]);
      k[j] = u ^ (((unsigned)((int)u >> 31)) | 0x80000000u);
    }

    unsigned P = 0;
    int kth = 16;
    int sz = 128;
    bool done = false;
    for (int b = 31; b >= 0; --b) {
      const unsigned tgt = (P >> b) | 1u;
      int c = 0;
#pragma unroll
      for (int j = 0; j < 8; ++j) {
        const unsigned long long bal = __ballot((k[j] >> b) == tgt);
        c += __popc((unsigned)((bal >> shift) & 0xFFFFull));
      }
      if (!done) {
        if (c >= kth) {
          P |= (1u << b);
          sz = c;
        } else {
          sz -= c;
          kth -= c;
        }
        done = (sz == kth);
      }
      if (__all(done)) break;
    }
    if (done) P -= 1u;  // select key >= old P (low bits zero); no ties remain

    // selection + rank (column order): gt first, then first `need` eq
    unsigned gtm[8], eqm[8];
    int gt_total = 0;
#pragma unroll
    for (int j = 0; j < 8; ++j) {
      const unsigned long long gb = __ballot(k[j] > P);
      const unsigned long long eb = __ballot(k[j] == P);
      gtm[j] = (unsigned)((gb >> shift) & 0xFFFFull);
      eqm[j] = (unsigned)((eb >> shift) & 0xFFFFull);
      gt_total += __popc(gtm[j]);
    }
    const int need = 16 - gt_total;
    int gt_pre = 0, eq_pre = 0;
#pragma unroll
    for (int j = 0; j < 8; ++j) {
      const bool isgt = k[j] > P;
      const bool iseq = k[j] == P;
      const int gtb = gt_pre + __popc(gtm[j] & below);
      const int eqb = eq_pre + __popc(eqm[j] & below);
      if (row < nrows && (isgt || (iseq && eqb < need))) {
        const int rank = gtb + (isgt ? min(eqb, need) : eqb);
        Vs[(size_t)row * 16 + rank] = v[j];
        Cs[(size_t)row * 16 + rank] = (unsigned char)(j * 16 + s);
      }
      gt_pre += __popc(gtm[j]);
      eq_pre += __popc(eqm[j]);
    }
  }
}

// ---------------- CSR build v2: two-level binning ---------------------------
__global__ __launch_bounds__(256) void bhist_kernel(const int* __restrict__ dst,
                                                    int* __restrict__ BC,
                                                    int E) {
  __shared__ int bh[NBUK];
  for (int i = threadIdx.x; i < NBUK; i += 256) bh[i] = 0;
  __syncthreads();
  const int stride = gridDim.x * 256;
  for (int e = blockIdx.x * 256 + threadIdx.x; e < E; e += stride)
    atomicAdd(&bh[dst[e] >> BSHIFT], 1);
  __syncthreads();
  for (int i = threadIdx.x; i < NBUK; i += 256)
    if (bh[i]) atomicAdd(&BC[i], bh[i]);
}

__global__ __launch_bounds__(NBUK) void bscan_kernel(
    const int* __restrict__ BC, int* __restrict__ bases,
    int* __restrict__ bcur, int* __restrict__ rs, int n, int E) {
  __shared__ int sc[NBUK];
  const int t = threadIdx.x;
  const int c = BC[t];
  sc[t] = c;
  __syncthreads();
  for (int st = 1; st < NBUK; st <<= 1) {
    const int v = sc[t];
    const int u = (t >= st) ? sc[t - st] : 0;
    __syncthreads();
    sc[t] = v + u;
    __syncthreads();
  }
  const int excl = sc[t] - c;
  bases[t] = excl;
  bcur[t] = excl;
  if (t == 0) rs[n] = E;
}

__global__ __launch_bounds__(256) void bin_kernel(
    const int* __restrict__ src, const int* __restrict__ dst,
    int* __restrict__ bcur, uint2* __restrict__ binned, int E, int chunk) {
  __shared__ int cnt[NBUK], off[NBUK], gbase[NBUK];
  __shared__ unsigned short bktof[4096];
  __shared__ uint2 buf[4096];
  const int t = threadIdx.x;
  const int beg = blockIdx.x * chunk;
  const int m = min(chunk, E - beg);
  if (m <= 0) return;

  for (int i = t; i < NBUK; i += 256) cnt[i] = 0;
  __syncthreads();

  int d[16], s[16], lp[16], bk[16];
#pragma unroll
  for (int i = 0; i < 16; ++i) {
    const int j = i * 256 + t;
    if (j < m) {
      d[i] = dst[beg + j];
      s[i] = src[beg + j];
      bk[i] = d[i] >> BSHIFT;
      lp[i] = atomicAdd(&cnt[bk[i]], 1);
    } else {
      bk[i] = -1;
    }
  }
  __syncthreads();

  for (int i = t; i < NBUK; i += 256) off[i] = cnt[i];
  __syncthreads();
  for (int st = 1; st < NBUK; st <<= 1) {
    int v0, v1, u0, u1;
    {
      const int i0 = t, i1 = t + 256;
      v0 = off[i0]; u0 = (i0 >= st) ? off[i0 - st] : 0;
      v1 = off[i1]; u1 = (i1 >= st) ? off[i1 - st] : 0;
    }
    __syncthreads();
    off[t] = v0 + u0;
    off[t + 256] = v1 + u1;
    __syncthreads();
  }

  for (int i = t; i < NBUK; i += 256) {
    const int c = cnt[i];
    if (c > 0) {
      gbase[i] = atomicAdd(&bcur[i], c);
      const int e0 = off[i] - c;
      for (int k = 0; k < c; ++k) bktof[e0 + k] = (unsigned short)i;
    }
  }
  __syncthreads();

#pragma unroll
  for (int i = 0; i < 16; ++i) {
    if (bk[i] >= 0) {
      buf[(off[bk[i]] - cnt[bk[i]]) + lp[i]] =
          make_uint2((unsigned)d[i], (unsigned)s[i]);
    }
  }
  __syncthreads();

  for (int j = t; j < m; j += 256) {
    const int b = bktof[j];
    const int e0 = off[b] - cnt[b];
    binned[gbase[b] + (j - e0)] = buf[j];
  }
}

__global__ __launch_bounds__(256) void bbuild_kernel(
    const int* __restrict__ bases, const int* __restrict__ BC,
    const uint2* __restrict__ binned, int* __restrict__ rs,
    int* __restrict__ csr_src, int n) {
  __shared__ int nd[256], sc[256], cur[256];
  const int b = blockIdx.x;
  const int t = threadIdx.x;
  const int base = bases[b];
  const int count = BC[b];
  const int node0 = b << BSHIFT;

  nd[t] = 0;
  __syncthreads();
  for (int i = t; i < count; i += 256)
    atomicAdd(&nd[binned[base + i].x & 255], 1);
  __syncthreads();

  sc[t] = nd[t];
  __syncthreads();
  for (int st = 1; st < 256; st <<= 1) {
    const int v = sc[t];
    const int u = (t >= st) ? sc[t - st] : 0;
    __syncthreads();
    sc[t] = v + u;
    __syncthreads();
  }
  const int excl = sc[t] - nd[t];
  cur[t] = excl;
  if (node0 + t < n) rs[node0 + t] = base + excl;
  __syncthreads();

  for (int i = t; i < count; i += 256) {
    const uint2 p = binned[base + i];
    const int pos = atomicAdd(&cur[p.x & 255], 1);
    csr_src[base + pos] = (int)p.y;
  }
}

// ---------------- Gather v6: LDS private-copy scatter -----------------------
__global__ __launch_bounds__(256) void gather6_kernel(
    const int* __restrict__ rs, const int* __restrict__ csr_src,
    const unsigned char* __restrict__ Cs, const float* __restrict__ Vs,
    const float* __restrict__ eps_p, short* __restrict__ Ah,
    short* __restrict__ Al, int nrows) {
  __shared__ __align__(16) float sv[4][16][16];          // staged vals
  __shared__ __align__(16) unsigned char scb[4][16][16]; // staged cols
  __shared__ float accb[4][4 * 132];                     // 4 copies/wave
  const int lane = threadIdx.x & 63;
  const int wid = threadIdx.x >> 6;
  const float e1 = 1.0f + *eps_p;
  const int ee = lane >> 2;   // staging: edge slot
  const int q = lane & 3;     // staging: quarter
  const int g = lane >> 4;    // scatter: edge group 0..3
  const int p = lane & 15;    // scatter: nnz index
  float* acc = accb[wid];
  float4* acc4 = (float4*)acc;

  for (int r = blockIdx.x * 4 + wid; r < nrows; r += gridDim.x * 4) {
    for (int i = lane; i < 132; i += 64)
      acc4[i] = make_float4(0.f, 0.f, 0.f, 0.f);

    const int beg = rs[r], end = rs[r + 1];
    for (int base = beg; base < end; base += 16) {
      const int cnt = min(16, end - base);
      if (ee < cnt) {
        const int s = csr_src[base + ee];
        if (q == 0) {
          const int4 c4 = *(const int4*)&Cs[(size_t)s * 16];
          *(int4*)&scb[wid][ee][0] = c4;
        }
        const float4 v = *(const float4*)&Vs[(size_t)s * 16 + q * 4];
        *(float4*)&sv[wid][ee][q * 4] = v;
      }
      for (int e = 0; e < cnt; e += 4) {
        const int eg = e + g;
        if (eg < cnt) {
          const int col = scb[wid][eg][p];
          const float val = sv[wid][eg][p];
          acc[g * 132 + col] += val;
        }
      }
    }
    if (lane < 16) {
      const int c = Cs[(size_t)r * 16 + lane];
      const float v = Vs[(size_t)r * 16 + lane];
      acc[c] += e1 * v;
    }
    const float a0 = acc[lane] + acc[132 + lane] + acc[264 + lane] +
                     acc[396 + lane];
    const float a1 = acc[64 + lane] + acc[132 + 64 + lane] +
                     acc[264 + 64 + lane] + acc[396 + 64 + lane];
    const unsigned h0 = rne_bf16(a0);
    const unsigned h1 = rne_bf16(a1);
    Ah[(size_t)r * 128 + lane] = (short)h0;
    Ah[(size_t)r * 128 + 64 + lane] = (short)h1;
    Al[(size_t)r * 128 + lane] =
        (short)rne_bf16(a0 - __uint_as_float(h0 << 16));
    Al[(size_t)r * 128 + 64 + lane] =
        (short)rne_bf16(a1 - __uint_as_float(h1 << 16));
  }
}

// ---------------------------------------------------------------------------
extern "C" void kernel_launch(void* const* d_in, const int* in_sizes, int n_in,
                              void* d_out, int out_size, void* d_ws,
                              size_t ws_size, hipStream_t stream) {
  const float* x = (const float*)d_in[0];
  const int* src = (const int*)d_in[1];
  const int* dst = (const int*)d_in[2];
  const float* W_in = (const float*)d_in[3];
  const float* b_in = (const float*)d_in[4];
  const float* W_lin = (const float*)d_in[5];
  const float* b_lin = (const float*)d_in[6];
  const float* eps = (const float*)d_in[7];
  const float* W_out = (const float*)d_in[8];
  const float* b_out = (const float*)d_in[9];
  float* out = (float*)d_out;

  const int n = in_sizes[0] / 128;
  const int E = in_sizes[1];

  char* w = (char*)d_ws;
  float* B = (float*)w;               w += (size_t)n * 128 * 4;
  unsigned char* Cs = (unsigned char*)w; w += (size_t)n * 16;
  float* Vs = (float*)w;              w += (size_t)n * 16 * 4;
  int* rs = (int*)w;                  w += (size_t)(n + 1) * 4;
  int* csr_src = (int*)w;             w += (size_t)E * 4;
  uint2* binned = (uint2*)w;          w += (size_t)E * 8;
  int* BC = (int*)w;                  w += NBUK * 4;
  int* bases = (int*)w;               w += NBUK * 4;
  int* bcur = (int*)w;                w += NBUK * 4;
  short* wtAll = (short*)w;           w += (size_t)114688 * 2;
  short* Ah = (short*)w;              w += (size_t)n * 128 * 2;
  short* Al = (short*)w;              w += (size_t)n * 128 * 2;

  short* wtIn = wtAll;
  short* wtL0 = wtAll + 32768;
  short* wtL1 = wtAll + 65536;
  short* wtOut = wtAll + 98304;

  const int ptiles = (n + 255) / 256;      // 256-row tiles (all GEMMs)
  const int nbuk_eff = (n + 255) >> BSHIFT;
  const int chunk = 4000;
  const int cblocks = (E + chunk - 1) / chunk;
  const dim3 blk(256);

  // ---- CSR build ----
  hipMemsetAsync(BC, 0, NBUK * 4, stream);
  bhist_kernel<<<256, blk, 0, stream>>>(dst, BC, E);
  bscan_kernel<<<1, NBUK, 0, stream>>>(BC, bases, bcur, rs, n, E);
  bin_kernel<<<cblocks, blk, 0, stream>>>(src, dst, bcur, binned, E, chunk);
  bbuild_kernel<<<nbuk_eff, blk, 0, stream>>>(bases, BC, binned, rs, csr_src,
                                              n);

  // ---- weights -> hi/lo bf16 ----
  wt_build_all_kernel<<<(57344 + 255) / 256, blk, 0, stream>>>(W_in, W_lin,
                                                               W_out, wtAll);

  // ---- h = relu(x @ W_in + b_in) -> planes ----
  gemm_in_kernel<<<ptiles, blk, 0, stream>>>(x, wtIn, wtIn + 16384, b_in, Ah,
                                             Al, n, ptiles);

  for (int l = 0; l < 2; ++l) {
    short* wt = l ? wtL1 : wtL0;
    gemm_pl_kernel<128><<<ptiles, blk, 0, stream>>>(
        Ah, Al, wt, wt + 16384, b_lin + (size_t)l * 128, B, n, ptiles);
    maxk_kernel<<<2048, blk, 0, stream>>>(B, Cs, Vs, n);
    gather6_kernel<<<2048, blk, 0, stream>>>(rs, csr_src, Cs, Vs, eps + l, Ah,
                                             Al, n);
  }

  gemm_pl_kernel<64><<<ptiles, blk, 0, stream>>>(Ah, Al, wtOut, wtOut + 8192,
                                                 b_out, out, n, ptiles);
}